// Round 5
// baseline (522.113 us; speedup 1.0000x reference)
//
#include <hip/hip_runtime.h>
#include <hip/hip_bf16.h>
#include <math.h>

typedef unsigned short u16;

// Wave-local LDS "barrier": each task's LDS region is touched by exactly ONE
// wave, and same-wave DS ops execute in order through the LDS pipe, so cross-
// lane visibility needs no s_barrier — only a compiler reorder fence plus a
// conservative lgkmcnt drain. ~tens of cycles vs ~hundreds for s_barrier.
#define WAVE_SYNC() asm volatile("s_waitcnt lgkmcnt(0)" ::: "memory")

// ---------- dtype helpers ----------
__device__ __forceinline__ float bf2f(u16 u) {
  union { unsigned int i; float f; } c;
  c.i = ((unsigned int)u) << 16;
  return c.f;
}

__device__ __forceinline__ u16 f2bf(float f) {
  union { float f; unsigned int i; } c;
  c.f = f;
  unsigned int x = c.i;
  unsigned int r = (x + 0x7fffu + ((x >> 16) & 1u)) >> 16; // RNE
  return (u16)r;
}

__device__ __forceinline__ float ld(const void* p, int i, int bf) {
  if (bf) return bf2f(((const u16*)p)[i]);
  return ((const float*)p)[i];
}

// ---------- runtime dtype detection (states ~ N(0,1)) ----------
__global__ void k_detect(const u16* __restrict__ states_raw, int* __restrict__ flag) {
  int score = 0;
  for (int i = 0; i < 128; ++i) {
    int e = (states_raw[i] >> 7) & 0xFF;
    if (e >= 97 && e <= 141) score++;
  }
  *flag = (score >= 104) ? 1 : 0;
}

// ---------- C51 scatter projection (exact reference semantics) ----------
__device__ __forceinline__ void proj_scatter(float* dst, float sup, float p) {
  float c = fminf(fmaxf(sup, -10.0f), 10.0f);
  float b = (c + 10.0f) / 0.4f;
  float l = floorf(b);
  float u = ceilf(b);
  float eq = (u == l) ? 1.0f : 0.0f;
  atomicAdd(&dst[(int)l], p * (u - b + eq));
  atomicAdd(&dst[(int)u], p * (b - l));
}

// Destination-bin bounds for proj of supports (-10+0.4t)*wv, t=0..50, wv>=0.
// Endpoints use IDENTICAL float ops as the scatter => conservative-exact.
__device__ __forceinline__ void proj_bounds(float wv, int& ML, int& MH) {
  float smin = (-10.0f + 0.4f * 0.0f)  * wv;
  float smax = (-10.0f + 0.4f * 50.0f) * wv;
  float bmin = (fminf(fmaxf(smin, -10.0f), 10.0f) + 10.0f) / 0.4f;
  float bmax = (fminf(fmaxf(smax, -10.0f), 10.0f) + 10.0f) / 0.4f;
  ML = (int)floorf(bmin);
  MH = (int)ceilf(bmax);
}

// ---------- support-tracked convolution (per-lane tap clamp) ----------
// qn[J] = sum_m kv[m]*q[J-m], m in [ML,MH], q claimed [LQ,HQ]. Output claimed
// [LQ+ML, HQ+MH], fully written. Never reads q outside [LQ,HQ].
__device__ __forceinline__ void conv_dyn(const float* __restrict__ q,
                                         float* __restrict__ qn,
                                         const float* __restrict__ kv,
                                         int ML, int MH, int LQ, int HQ,
                                         int tid, int nthr)
{
  const int Lout = LQ + ML, Hout = HQ + MH;
  for (int J = Lout + tid; J <= Hout; J += nthr) {
    int mlo = ML > J - HQ ? ML : J - HQ;
    int mhi = MH < J - LQ ? MH : J - LQ;
    float acc = 0.f;
    for (int m = mlo; m <= mhi; ++m)
      acc = fmaf(kv[m], q[J - m], acc);
    qn[J] = acc;
  }
}

// =================== Kernel 1: per-sample hypernet MLPs ===================
__global__ __launch_bounds__(64) void k_mlp(
    const void* __restrict__ states,
    const void* __restrict__ hw1_w1, const void* __restrict__ hw1_b1,
    const void* __restrict__ hw1_w2, const void* __restrict__ hw1_b2,
    const void* __restrict__ hb1_w,  const void* __restrict__ hb1_b,
    const void* __restrict__ hwf_w1, const void* __restrict__ hwf_b1,
    const void* __restrict__ hwf_w2, const void* __restrict__ hwf_b2,
    const void* __restrict__ v_w1,   const void* __restrict__ v_b1,
    const void* __restrict__ v_w2,   const void* __restrict__ v_b2,
    float* __restrict__ w1_ws, float* __restrict__ b1_ws,
    float* __restrict__ wf_ws, float* __restrict__ v_ws,
    const int* __restrict__ flag)
{
  const int n = blockIdx.x;
  const int tid = threadIdx.x;
  const int bf = *flag;
  __shared__ float s[128];
  __shared__ float h1[64];
  __shared__ float hf[64];
  __shared__ float vh[32];

  s[tid]      = ld(states, n * 128 + tid, bf);
  s[tid + 64] = ld(states, n * 128 + 64 + tid, bf);
  __syncthreads();

  auto dot128 = [&](const void* w, int row) {
    float acc = 0.f;
    for (int i = 0; i < 128; ++i)
      acc = fmaf(ld(w, row * 128 + i, bf), s[i], acc);
    return acc;
  };
  auto dot64 = [&](const void* w, int row, const float* h) {
    float acc = 0.f;
    for (int i = 0; i < 64; ++i)
      acc = fmaf(ld(w, row * 64 + i, bf), h[i], acc);
    return acc;
  };

  h1[tid] = fmaxf(dot128(hw1_w1, tid) + ld(hw1_b1, tid, bf), 0.f);
  hf[tid] = fmaxf(dot128(hwf_w1, tid) + ld(hwf_b1, tid, bf), 0.f);
  if (tid < 32) {
    vh[tid] = fmaxf(dot128(v_w1, tid) + ld(v_b1, tid, bf), 0.f);
    b1_ws[n * 32 + tid] = dot128(hb1_w, tid) + ld(hb1_b, tid, bf);
  }
  __syncthreads();

  for (int o = tid; o < 256; o += 64)
    w1_ws[n * 256 + o] = fabsf(dot64(hw1_w2, o, h1) + ld(hw1_b2, o, bf));
  if (tid < 32)
    wf_ws[n * 32 + tid] = fabsf(dot64(hwf_w2, tid, hf) + ld(hwf_b2, tid, bf));
  if (tid == 0) {
    float acc = ld(v_b2, 0, bf);
    for (int e = 0; e < 32; ++e) acc = fmaf(ld(v_w2, e, bf), vh[e], acc);
    v_ws[n] = acc;
  }
}

// ======= Kernel 2: 2 tasks per 128-thread block, one wave per task,
//                   NO block barriers (wave-local LDS sync only) =======
__global__ __launch_bounds__(128) void k_perembed(
    const void* __restrict__ aq,          // (1024, 8, 51)
    const float* __restrict__ w1_ws, const float* __restrict__ b1_ws,
    const float* __restrict__ wf_ws, float* __restrict__ xw_ws,
    const int* __restrict__ flag)
{
  __shared__ float Ab[2][456];
  __shared__ float Bb[2][456];
  __shared__ float kvb[2][52];
  __shared__ float x2b[2][52];

  const int w    = threadIdx.x >> 6;
  const int lane = threadIdx.x & 63;
  const int task = blockIdx.x * 2 + w;
  const int n = task >> 5;
  const int e = task & 31;
  const int bf = *flag;

  float* A  = Ab[w];
  float* B  = Bb[w];
  float* kv = kvb[w];
  float* x2 = x2b[w];

  // ---- agent 0: bounds + zero claimed + scatter into A (base 52) ----
  float wv0 = w1_ws[n * 256 + e * 8 + 0];
  int ML0, MH0;
  proj_bounds(wv0, ML0, MH0);
  for (int m = ML0 + lane; m <= MH0; m += 64) A[52 + m] = 0.f;
  if (lane < 52) x2[lane] = 0.f;
  WAVE_SYNC();
  if (lane < 51) {
    float p = ld(aq, (n * 8 + 0) * 51 + lane, bf);
    proj_scatter(A + 52, (-10.0f + 0.4f * lane) * wv0, p);
  }
  WAVE_SYNC();

  int LQ = 52 + ML0, HQ = 52 + MH0;
  float* q = A;
  float* qn = B;
  for (int a = 1; a < 8; ++a) {
    float wv = w1_ws[n * 256 + e * 8 + a];
    int ML, MH;
    proj_bounds(wv, ML, MH);
    for (int m = ML + lane; m <= MH; m += 64) kv[m] = 0.f;
    WAVE_SYNC();
    if (lane < 51) {
      float p = ld(aq, (n * 8 + a) * 51 + lane, bf);
      proj_scatter(kv, (-10.0f + 0.4f * lane) * wv, p);
    }
    WAVE_SYNC();
    conv_dyn(q, qn, kv, ML, MH, LQ, HQ, lane, 64);
    WAVE_SYNC();
    LQ += ML; HQ += MH;
    float* tmp = q; q = qn; qn = tmp;
  }

  // ---- elu stage: only q's claimed support contributes (p=0 elsewhere) ----
  float b1v = b1_ws[n * 32 + e];
  float ahi = 0.f;
  for (int J = LQ + lane; J <= HQ; J += 64) {
    int t = J - 52;                       // in [0,400] by construction
    float sup = (-80.0f + 0.4f * t) + b1v;
    sup = (sup > 0.f) ? sup : expm1f(sup);
    float p = q[J];
    if (sup >= 10.0f) ahi += p;           // clips exactly to bin 50
    else proj_scatter(x2, sup, p);        // elu >= -1 > -10: no low clip
  }
  if (ahi != 0.f) atomicAdd(&x2[50], ahi);
  WAVE_SYNC();

  // ---- xw = proj(atoms*wf, x2): bounds from wf (recomputable in k_final) ----
  float wfv = wf_ws[n * 32 + e];
  int MLf, MHf;
  proj_bounds(wfv, MLf, MHf);
  for (int m = MLf + lane; m <= MHf; m += 64) kv[m] = 0.f;
  WAVE_SYNC();
  if (lane < 51) proj_scatter(kv, (-10.0f + 0.4f * lane) * wfv, x2[lane]);
  WAVE_SYNC();
  for (int m = MLf + lane; m <= MHf; m += 64)
    xw_ws[task * 51 + m] = kv[m];
}

// ====== Kernel 3: ONE WAVE per sample (4 samples / 256-thr block),
//                  31-conv chain + final projection, no block barriers ======
__global__ __launch_bounds__(256) void k_final(
    const float* __restrict__ xw_ws, const float* __restrict__ wf_ws,
    const float* __restrict__ v_ws,
    void* __restrict__ out, const int* __restrict__ flag)
{
  __shared__ float Ab[4][1656];
  __shared__ float Bb[4][1656];
  __shared__ float kvb[4][52];
  __shared__ float obb[4][52];

  const int w    = threadIdx.x >> 6;
  const int lane = threadIdx.x & 63;
  const int n    = blockIdx.x * 4 + w;
  const int bf   = *flag;

  float* A  = Ab[w];
  float* B  = Bb[w];
  float* kv = kvb[w];
  float* ob = obb[w];

  // e = 0 seed: claimed bounds from wf[n,0]
  int ML0, MH0;
  proj_bounds(wf_ws[n * 32 + 0], ML0, MH0);
  for (int m = ML0 + lane; m <= MH0; m += 64)
    A[52 + m] = xw_ws[(n * 32 + 0) * 51 + m];
  if (lane < 52) ob[lane] = 0.f;
  WAVE_SYNC();

  int LQ = 52 + ML0, HQ = 52 + MH0;
  float* q = A;
  float* qn = B;
  for (int e = 1; e < 32; ++e) {
    int ML, MH;
    proj_bounds(wf_ws[n * 32 + e], ML, MH);
    for (int m = ML + lane; m <= MH; m += 64)
      kv[m] = xw_ws[(n * 32 + e) * 51 + m];
    WAVE_SYNC();
    conv_dyn(q, qn, kv, ML, MH, LQ, HQ, lane, 64);
    WAVE_SYNC();
    LQ += ML; HQ += MH;
    float* tmp = q; q = qn; qn = tmp;
  }

  // final projection over claimed support only (p=0 outside)
  float vv = v_ws[n];
  float alo = 0.f, ahi = 0.f;
  for (int J = LQ + lane; J <= HQ; J += 64) {
    int t = J - 52;                       // in [0,1600] by construction
    float sup = (-320.0f + 0.4f * t) + vv;
    float p = q[J];
    if (sup <= -10.0f)      alo += p;     // bin 0
    else if (sup >= 10.0f)  ahi += p;     // bin 50
    else proj_scatter(ob, sup, p);
  }
  if (alo != 0.f) atomicAdd(&ob[0], alo);
  if (ahi != 0.f) atomicAdd(&ob[50], ahi);
  WAVE_SYNC();

  if (lane < 51) {
    if (bf) ((u16*)out)[n * 51 + lane] = f2bf(ob[lane]);
    else    ((float*)out)[n * 51 + lane] = ob[lane];
  }
}

// =========================== launcher ===========================
extern "C" void kernel_launch(void* const* d_in, const int* in_sizes, int n_in,
                              void* d_out, int out_size, void* d_ws, size_t ws_size,
                              hipStream_t stream)
{
  float* ws    = (float*)d_ws;
  float* w1_ws = ws;                       // 1024*256
  float* b1_ws = w1_ws + 1024 * 256;       // 1024*32
  float* wf_ws = b1_ws + 1024 * 32;        // 1024*32
  float* v_ws  = wf_ws + 1024 * 32;        // 1024
  float* xw_ws = v_ws  + 1024;             // 1024*32*51
  int*   flag  = (int*)(xw_ws + 1024 * 32 * 51);

  k_detect<<<1, 1, 0, stream>>>((const u16*)d_in[1], flag);

  k_mlp<<<1024, 64, 0, stream>>>(d_in[1],
      d_in[2], d_in[3], d_in[4], d_in[5], d_in[6], d_in[7],
      d_in[8], d_in[9], d_in[10], d_in[11], d_in[12], d_in[13],
      d_in[14], d_in[15],
      w1_ws, b1_ws, wf_ws, v_ws, flag);

  k_perembed<<<16384, 128, 0, stream>>>(d_in[0], w1_ws, b1_ws, wf_ws, xw_ws, flag);

  k_final<<<256, 256, 0, stream>>>(xw_ws, wf_ws, v_ws, d_out, flag);
}

// Round 6
// 416.011 us; speedup vs baseline: 1.2550x; 1.2550x over previous
//
#include <hip/hip_runtime.h>
#include <hip/hip_bf16.h>
#include <math.h>

typedef unsigned short u16;

// Wave-local LDS fence: each task's LDS region is touched by exactly ONE wave;
// lgkmcnt(0) drains this wave's LDS ops (incl. atomics) so all lanes see them.
#define WAVE_SYNC() asm volatile("s_waitcnt lgkmcnt(0)" ::: "memory")

// ---------- dtype helpers ----------
__device__ __forceinline__ float bf2f(u16 u) {
  union { unsigned int i; float f; } c;
  c.i = ((unsigned int)u) << 16;
  return c.f;
}
__device__ __forceinline__ float bflo(unsigned int u) {
  union { unsigned int i; float f; } c;
  c.i = u << 16;
  return c.f;
}
__device__ __forceinline__ float bfhi(unsigned int u) {
  union { unsigned int i; float f; } c;
  c.i = u & 0xffff0000u;
  return c.f;
}
__device__ __forceinline__ u16 f2bf(float f) {
  union { float f; unsigned int i; } c;
  c.f = f;
  unsigned int x = c.i;
  unsigned int r = (x + 0x7fffu + ((x >> 16) & 1u)) >> 16; // RNE
  return (u16)r;
}

// ---------- runtime dtype detection (states ~ N(0,1)) ----------
__global__ void k_detect(const u16* __restrict__ states_raw, int* __restrict__ flag) {
  int score = 0;
  for (int i = 0; i < 128; ++i) {
    int e = (states_raw[i] >> 7) & 0xFF;
    if (e >= 97 && e <= 141) score++;
  }
  *flag = (score >= 104) ? 1 : 0;
}

// ---------- C51 scatter projection (exact reference semantics) ----------
__device__ __forceinline__ void proj_scatter(float* dst, float sup, float p) {
  float c = fminf(fmaxf(sup, -10.0f), 10.0f);
  float b = (c + 10.0f) / 0.4f;
  float l = floorf(b);
  float u = ceilf(b);
  float eq = (u == l) ? 1.0f : 0.0f;
  atomicAdd(&dst[(int)l], p * (u - b + eq));
  atomicAdd(&dst[(int)u], p * (b - l));
}

// Destination-bin bounds for proj of supports (-10+0.4t)*wv, t=0..50, wv>=0.
// Endpoints use IDENTICAL float ops as the scatter => conservative-exact.
// Note ML >= 0 always (b in [0,50] after clip).
__device__ __forceinline__ void proj_bounds(float wv, int& ML, int& MH) {
  float smin = (-10.0f + 0.4f * 0.0f)  * wv;
  float smax = (-10.0f + 0.4f * 50.0f) * wv;
  float bmin = (fminf(fmaxf(smin, -10.0f), 10.0f) + 10.0f) / 0.4f;
  float bmax = (fminf(fmaxf(smax, -10.0f), 10.0f) + 10.0f) / 0.4f;
  ML = (int)floorf(bmin);
  MH = (int)ceilf(bmax);
}

// ---------- padded-tap convolution (batchable LDS loads) ----------
// Taps padded to W (mult of 8): kv[ML..ML+W) zero beyond MH; q guard bands
// [LQ-W+1,LQ) and (HQ,HQ+(MH-ML)] pre-zeroed by caller. Uniform trip counts
// => compiler batches the 16 ds_reads per chunk behind ONE lgkmcnt wait.
__device__ __forceinline__ void conv_pad(const float* __restrict__ q,
                                         float* __restrict__ qn,
                                         const float* __restrict__ kv,
                                         int ML, int MH, int W,
                                         int LQ, int HQ, int lane)
{
  const int Lout = LQ + ML, Hout = HQ + MH;
  for (int J = Lout + lane; J <= Hout; J += 64) {
    const float* qp = q + (J - ML);
    float acc = 0.f;
    for (int c = 0; c < W; c += 8) {
      const float* kc = kv + ML + c;
      const float* qc = qp - c;
      float k0 = kc[0], k1 = kc[1], k2 = kc[2], k3 = kc[3];
      float k4 = kc[4], k5 = kc[5], k6 = kc[6], k7 = kc[7];
      float x0 = qc[0],  x1 = qc[-1], x2 = qc[-2], x3 = qc[-3];
      float x4 = qc[-4], x5 = qc[-5], x6 = qc[-6], x7 = qc[-7];
      acc = fmaf(k0, x0, acc); acc = fmaf(k1, x1, acc);
      acc = fmaf(k2, x2, acc); acc = fmaf(k3, x3, acc);
      acc = fmaf(k4, x4, acc); acc = fmaf(k5, x5, acc);
      acc = fmaf(k6, x6, acc); acc = fmaf(k7, x7, acc);
    }
    qn[J] = acc;
  }
}

// =================== Kernel 1: per-sample hypernet MLPs ===================
template<int BF>
__device__ __forceinline__ float ldt(const void* p, int i) {
  if (BF) return bf2f(((const u16*)p)[i]);
  return ((const float*)p)[i];
}

template<int BF>
__device__ __forceinline__ float dot128_t(const void* w, int row, const float* s) {
  float acc = 0.f;
  if (BF) {
    const uint4* p = (const uint4*)((const u16*)w + row * 128);
#pragma unroll
    for (int i = 0; i < 16; ++i) {
      uint4 v = p[i];
      int b = i * 8;
      acc = fmaf(bflo(v.x), s[b + 0], acc); acc = fmaf(bfhi(v.x), s[b + 1], acc);
      acc = fmaf(bflo(v.y), s[b + 2], acc); acc = fmaf(bfhi(v.y), s[b + 3], acc);
      acc = fmaf(bflo(v.z), s[b + 4], acc); acc = fmaf(bfhi(v.z), s[b + 5], acc);
      acc = fmaf(bflo(v.w), s[b + 6], acc); acc = fmaf(bfhi(v.w), s[b + 7], acc);
    }
  } else {
    const float4* p = (const float4*)((const float*)w + row * 128);
#pragma unroll
    for (int i = 0; i < 32; ++i) {
      float4 v = p[i];
      int b = i * 4;
      acc = fmaf(v.x, s[b + 0], acc); acc = fmaf(v.y, s[b + 1], acc);
      acc = fmaf(v.z, s[b + 2], acc); acc = fmaf(v.w, s[b + 3], acc);
    }
  }
  return acc;
}

template<int BF>
__device__ __forceinline__ float dot64_t(const void* w, int row, const float* h) {
  float acc = 0.f;
  if (BF) {
    const uint4* p = (const uint4*)((const u16*)w + row * 64);
#pragma unroll
    for (int i = 0; i < 8; ++i) {
      uint4 v = p[i];
      int b = i * 8;
      acc = fmaf(bflo(v.x), h[b + 0], acc); acc = fmaf(bfhi(v.x), h[b + 1], acc);
      acc = fmaf(bflo(v.y), h[b + 2], acc); acc = fmaf(bfhi(v.y), h[b + 3], acc);
      acc = fmaf(bflo(v.z), h[b + 4], acc); acc = fmaf(bfhi(v.z), h[b + 5], acc);
      acc = fmaf(bflo(v.w), h[b + 6], acc); acc = fmaf(bfhi(v.w), h[b + 7], acc);
    }
  } else {
    const float4* p = (const float4*)((const float*)w + row * 64);
#pragma unroll
    for (int i = 0; i < 16; ++i) {
      float4 v = p[i];
      int b = i * 4;
      acc = fmaf(v.x, h[b + 0], acc); acc = fmaf(v.y, h[b + 1], acc);
      acc = fmaf(v.z, h[b + 2], acc); acc = fmaf(v.w, h[b + 3], acc);
    }
  }
  return acc;
}

template<int BF>
__device__ __forceinline__ void mlp_body(
    const void* states,
    const void* hw1_w1, const void* hw1_b1, const void* hw1_w2, const void* hw1_b2,
    const void* hb1_w,  const void* hb1_b,
    const void* hwf_w1, const void* hwf_b1, const void* hwf_w2, const void* hwf_b2,
    const void* v_w1,   const void* v_b1,   const void* v_w2,   const void* v_b2,
    float* w1_ws, float* b1_ws, float* wf_ws, float* v_ws,
    int n, int tid, float* s, float* h1, float* hf, float* vh)
{
  s[tid]      = ldt<BF>(states, n * 128 + tid);
  s[tid + 64] = ldt<BF>(states, n * 128 + 64 + tid);
  __syncthreads();

  h1[tid] = fmaxf(dot128_t<BF>(hw1_w1, tid, s) + ldt<BF>(hw1_b1, tid), 0.f);
  hf[tid] = fmaxf(dot128_t<BF>(hwf_w1, tid, s) + ldt<BF>(hwf_b1, tid), 0.f);
  if (tid < 32) {
    vh[tid] = fmaxf(dot128_t<BF>(v_w1, tid, s) + ldt<BF>(v_b1, tid), 0.f);
    b1_ws[n * 32 + tid] = dot128_t<BF>(hb1_w, tid, s) + ldt<BF>(hb1_b, tid);
  }
  __syncthreads();

#pragma unroll
  for (int k = 0; k < 4; ++k) {
    int o = tid + 64 * k;
    w1_ws[n * 256 + o] = fabsf(dot64_t<BF>(hw1_w2, o, h1) + ldt<BF>(hw1_b2, o));
  }
  if (tid < 32)
    wf_ws[n * 32 + tid] = fabsf(dot64_t<BF>(hwf_w2, tid, hf) + ldt<BF>(hwf_b2, tid));
  if (tid == 0) {
    float acc = ldt<BF>(v_b2, 0);
    for (int e = 0; e < 32; ++e) acc = fmaf(ldt<BF>(v_w2, e), vh[e], acc);
    v_ws[n] = acc;
  }
}

__global__ __launch_bounds__(64) void k_mlp(
    const void* __restrict__ states,
    const void* __restrict__ hw1_w1, const void* __restrict__ hw1_b1,
    const void* __restrict__ hw1_w2, const void* __restrict__ hw1_b2,
    const void* __restrict__ hb1_w,  const void* __restrict__ hb1_b,
    const void* __restrict__ hwf_w1, const void* __restrict__ hwf_b1,
    const void* __restrict__ hwf_w2, const void* __restrict__ hwf_b2,
    const void* __restrict__ v_w1,   const void* __restrict__ v_b1,
    const void* __restrict__ v_w2,   const void* __restrict__ v_b2,
    float* __restrict__ w1_ws, float* __restrict__ b1_ws,
    float* __restrict__ wf_ws, float* __restrict__ v_ws,
    const int* __restrict__ flag)
{
  __shared__ float s[128];
  __shared__ float h1[64];
  __shared__ float hf[64];
  __shared__ float vh[32];
  const int n = blockIdx.x;
  const int tid = threadIdx.x;
  if (*flag)
    mlp_body<1>(states, hw1_w1, hw1_b1, hw1_w2, hw1_b2, hb1_w, hb1_b,
                hwf_w1, hwf_b1, hwf_w2, hwf_b2, v_w1, v_b1, v_w2, v_b2,
                w1_ws, b1_ws, wf_ws, v_ws, n, tid, s, h1, hf, vh);
  else
    mlp_body<0>(states, hw1_w1, hw1_b1, hw1_w2, hw1_b2, hb1_w, hb1_b,
                hwf_w1, hwf_b1, hwf_w2, hwf_b2, v_w1, v_b1, v_w2, v_b2,
                w1_ws, b1_ws, wf_ws, v_ws, n, tid, s, h1, hf, vh);
}

// ======= Kernel 2: 2 tasks per 128-thread block, one wave per task =======
__global__ __launch_bounds__(128) void k_perembed(
    const void* __restrict__ aq,          // (1024, 8, 51)
    const float* __restrict__ w1_ws, const float* __restrict__ b1_ws,
    const float* __restrict__ wf_ws, float* __restrict__ xw_ws,
    const int* __restrict__ flag)
{
  __shared__ float Ab[2][520];
  __shared__ float Bb[2][520];
  __shared__ float kvb[2][112];
  __shared__ float x2b[2][52];

  const int w    = threadIdx.x >> 6;
  const int lane = threadIdx.x & 63;
  const int task = blockIdx.x * 2 + w;
  const int n = task >> 5;
  const int e = task & 31;
  const int bf = *flag;

  float* A  = Ab[w];
  float* B  = Bb[w];
  float* kv = kvb[w];
  float* x2 = x2b[w];

  // ---- prefetch: 8 agent probs (independent loads, one wait), w1 row, scalars
  float pv[8];
  if (bf) {
    const u16* p = (const u16*)aq + n * 408 + lane;
#pragma unroll
    for (int a = 0; a < 8; ++a) pv[a] = (lane < 51) ? bf2f(p[a * 51]) : 0.f;
  } else {
    const float* p = (const float*)aq + n * 408 + lane;
#pragma unroll
    for (int a = 0; a < 8; ++a) pv[a] = (lane < 51) ? p[a * 51] : 0.f;
  }
  float wreg = (lane < 8) ? w1_ws[n * 256 + e * 8 + lane] : 0.f;
  float b1v  = b1_ws[n * 32 + e];
  float wfv  = wf_ws[n * 32 + e];

  if (lane < 52) x2[lane] = 0.f;

  // ---- seed: agent 0 scattered into A (data base 64) ----
  float wv0 = __shfl(wreg, 0);
  int ML0, MH0;
  proj_bounds(wv0, ML0, MH0);
  if (lane <= MH0 - ML0) A[64 + ML0 + lane] = 0.f;
  WAVE_SYNC();
  if (lane < 51) proj_scatter(A + 64, (-10.0f + 0.4f * lane) * wv0, pv[0]);
  WAVE_SYNC();

  int LQ = 64 + ML0, HQ = 64 + MH0;
  float* q = A;
  float* qn = B;
#pragma unroll
  for (int a = 1; a < 8; ++a) {
    float wv = __shfl(wreg, a);
    int ML, MH;
    proj_bounds(wv, ML, MH);
    int T = MH - ML;
    int W = (T + 8) & ~7;                 // padded taps, mult of 8, >= T+1
    if (lane < W)     kv[ML + lane] = 0.f;
    if (lane < W - 1) q[LQ - 1 - lane] = 0.f;   // lower guard
    if (lane < T)     q[HQ + 1 + lane] = 0.f;   // upper guard
    WAVE_SYNC();
    if (lane < 51) proj_scatter(kv, (-10.0f + 0.4f * lane) * wv, pv[a]);
    WAVE_SYNC();
    conv_pad(q, qn, kv, ML, MH, W, LQ, HQ, lane);
    WAVE_SYNC();
    LQ += ML; HQ += MH;
    float* t_ = q; q = qn; qn = t_;
  }

  // ---- elu stage: only claimed support contributes (p=0 elsewhere) ----
  float ahi = 0.f;
  for (int J = LQ + lane; J <= HQ; J += 64) {
    int t = J - 64;                       // in [0,400] by construction
    float sup = (-80.0f + 0.4f * t) + b1v;
    sup = (sup > 0.f) ? sup : expm1f(sup);
    float p = q[J];
    if (sup >= 10.0f) ahi += p;           // clips exactly to bin 50
    else proj_scatter(x2, sup, p);        // elu >= -1 > -10: no low clip
  }
  if (ahi != 0.f) atomicAdd(&x2[50], ahi);
  WAVE_SYNC();

  // ---- xw = proj(atoms*wf, x2): bounds recomputable in k_final ----
  int MLf, MHf;
  proj_bounds(wfv, MLf, MHf);
  if (lane <= MHf - MLf) kv[MLf + lane] = 0.f;
  WAVE_SYNC();
  if (lane < 51) proj_scatter(kv, (-10.0f + 0.4f * lane) * wfv, x2[lane]);
  WAVE_SYNC();
  if (lane <= MHf - MLf) xw_ws[task * 51 + MLf + lane] = kv[MLf + lane];
}

// ====== Kernel 3: ONE WAVE per sample, pipelined kernel-row prefetch ======
__global__ __launch_bounds__(64) void k_final(
    const float* __restrict__ xw_ws, const float* __restrict__ wf_ws,
    const float* __restrict__ v_ws,
    void* __restrict__ out, const int* __restrict__ flag)
{
  __shared__ float A[1720];
  __shared__ float B[1720];
  __shared__ float kv[112];
  __shared__ float ob[52];

  const int n    = blockIdx.x;
  const int lane = threadIdx.x;
  const int bf   = *flag;

  float wfreg = (lane < 32) ? wf_ws[n * 32 + lane] : 0.f;
  float vv    = v_ws[n];
  if (lane < 52) ob[lane] = 0.f;

  // e = 0 seed (direct copy, claimed fully written)
  float wv0 = __shfl(wfreg, 0);
  int ML0, MH0;
  proj_bounds(wv0, ML0, MH0);
  if (lane <= MH0 - ML0)
    A[64 + ML0 + lane] = xw_ws[(n * 32 + 0) * 51 + ML0 + lane];

  int LQ = 64 + ML0, HQ = 64 + MH0;
  float* q = A;
  float* qn = B;

  // prefetch e=1 kernel row
  int MLn, MHn;
  { float wvn = __shfl(wfreg, 1); proj_bounds(wvn, MLn, MHn); }
  float nv = (lane <= MHn - MLn) ? xw_ws[(n * 32 + 1) * 51 + MLn + lane] : 0.f;

  for (int e = 1; e < 32; ++e) {
    int ML = MLn, MH = MHn;
    int T = MH - ML;
    int W = (T + 8) & ~7;
    if (lane < W)     kv[ML + lane] = (lane <= T) ? nv : 0.f;
    if (lane < W - 1) q[LQ - 1 - lane] = 0.f;
    if (lane < T)     q[HQ + 1 + lane] = 0.f;
    if (e < 31) {                         // issue next row load (overlaps conv)
      float wvn = __shfl(wfreg, e + 1);
      proj_bounds(wvn, MLn, MHn);
      nv = (lane <= MHn - MLn) ? xw_ws[(n * 32 + e + 1) * 51 + MLn + lane] : 0.f;
    }
    WAVE_SYNC();
    conv_pad(q, qn, kv, ML, MH, W, LQ, HQ, lane);
    WAVE_SYNC();
    LQ += ML; HQ += MH;
    float* t_ = q; q = qn; qn = t_;
  }

  // final projection over claimed support only (p=0 outside)
  float alo = 0.f, ahi = 0.f;
  for (int J = LQ + lane; J <= HQ; J += 64) {
    int t = J - 64;                       // in [0,1600] by construction
    float sup = (-320.0f + 0.4f * t) + vv;
    float p = q[J];
    if (sup <= -10.0f)      alo += p;     // bin 0
    else if (sup >= 10.0f)  ahi += p;     // bin 50
    else proj_scatter(ob, sup, p);
  }
  if (alo != 0.f) atomicAdd(&ob[0], alo);
  if (ahi != 0.f) atomicAdd(&ob[50], ahi);
  WAVE_SYNC();

  if (lane < 51) {
    if (bf) ((u16*)out)[n * 51 + lane] = f2bf(ob[lane]);
    else    ((float*)out)[n * 51 + lane] = ob[lane];
  }
}

// =========================== launcher ===========================
extern "C" void kernel_launch(void* const* d_in, const int* in_sizes, int n_in,
                              void* d_out, int out_size, void* d_ws, size_t ws_size,
                              hipStream_t stream)
{
  float* ws    = (float*)d_ws;
  float* w1_ws = ws;                       // 1024*256
  float* b1_ws = w1_ws + 1024 * 256;       // 1024*32
  float* wf_ws = b1_ws + 1024 * 32;        // 1024*32
  float* v_ws  = wf_ws + 1024 * 32;        // 1024
  float* xw_ws = v_ws  + 1024;             // 1024*32*51
  int*   flag  = (int*)(xw_ws + 1024 * 32 * 51);

  k_detect<<<1, 1, 0, stream>>>((const u16*)d_in[1], flag);

  k_mlp<<<1024, 64, 0, stream>>>(d_in[1],
      d_in[2], d_in[3], d_in[4], d_in[5], d_in[6], d_in[7],
      d_in[8], d_in[9], d_in[10], d_in[11], d_in[12], d_in[13],
      d_in[14], d_in[15],
      w1_ws, b1_ws, wf_ws, v_ws, flag);

  k_perembed<<<16384, 128, 0, stream>>>(d_in[0], w1_ws, b1_ws, wf_ws, xw_ws, flag);

  k_final<<<1024, 64, 0, stream>>>(xw_ws, wf_ws, v_ws, d_out, flag);
}

// Round 7
// 270.222 us; speedup vs baseline: 1.9322x; 1.5395x over previous
//
#include <hip/hip_runtime.h>
#include <hip/hip_bf16.h>
#include <math.h>

typedef unsigned short u16;

// Compiler memory fence + drain of this wave's LDS ops. Each task's LDS region
// is touched by exactly ONE wave; same-wave DS ops execute in order.
#define WAVE_SYNC() asm volatile("s_waitcnt lgkmcnt(0)" ::: "memory")

// ---------- dtype helpers ----------
__device__ __forceinline__ float bf2f(u16 u) {
  union { unsigned int i; float f; } c;
  c.i = ((unsigned int)u) << 16;
  return c.f;
}
__device__ __forceinline__ float bflo(unsigned int u) {
  union { unsigned int i; float f; } c; c.i = u << 16; return c.f;
}
__device__ __forceinline__ float bfhi(unsigned int u) {
  union { unsigned int i; float f; } c; c.i = u & 0xffff0000u; return c.f;
}
__device__ __forceinline__ u16 f2bf(float f) {
  union { float f; unsigned int i; } c;
  c.f = f;
  unsigned int x = c.i;
  unsigned int r = (x + 0x7fffu + ((x >> 16) & 1u)) >> 16; // RNE
  return (u16)r;
}

// Destination-bin bounds for proj of supports (-10+0.4t)*wv, t=0..50, wv>=0.
// Endpoints use IDENTICAL float ops as the projection => conservative-exact.
__device__ __forceinline__ void proj_bounds(float wv, int& ML, int& MH) {
  float smin = (-10.0f + 0.4f * 0.0f)  * wv;
  float smax = (-10.0f + 0.4f * 50.0f) * wv;
  float bmin = (fminf(fmaxf(smin, -10.0f), 10.0f) + 10.0f) / 0.4f;
  float bmax = (fminf(fmaxf(smax, -10.0f), 10.0f) + 10.0f) / 0.4f;
  ML = (int)floorf(bmin);
  MH = (int)ceilf(bmax);
}

// ---------- atomic-free projection via segmented scan ----------
// Keys l(t)=floor(b(t)) are monotone in t (monotone support). Segmented
// inclusive scan over lanes; run-end lanes (unique keys) store g1[l]=sum(ml),
// g2[l+1]=sum(mu) -> no collisions, no atomics. Bin j = g1[j]+g2[j].
// Chunked (64/t per pass) with cross-chunk run carry for span>64.
// supp(t, act, sup, p): exact ref float ops for sup; p=0 when !act.
template<typename SUPP>
__device__ __forceinline__ void proj_scan(float* __restrict__ g1,
                                          float* __restrict__ g2,
                                          int span, int lane, SUPP supp)
{
  if (lane < 52) g1[lane] = 0.f;
  if (lane < 53) g2[lane] = 0.f;
  float cml = 0.f, cmu = 0.f;
  int ck = -1;
  for (int base = 0; base < span; base += 64) {
    int t = base + lane;
    bool act = (t < span);
    int tc = act ? t : (span - 1);
    float sup, p;
    supp(tc, act, sup, p);
    float c  = fminf(fmaxf(sup, -10.0f), 10.0f);
    float b  = (c + 10.0f) / 0.4f;          // exact ref semantics (no *2.5)
    float l  = floorf(b);
    float u  = ceilf(b);
    float eq = (u == l) ? 1.0f : 0.0f;
    float ml = p * (u - b + eq);
    float mu = p * (b - l);
    int   li = (int)l;
    bool last = (base + 64 >= span);
    if (lane == 0 && ck >= 0) {
      if (ck == li) { ml += cml; mu += cmu; }      // run continues
      else          { g1[ck] = cml; g2[ck + 1] = cmu; }  // flush ended run
    }
#pragma unroll
    for (int d = 1; d < 64; d <<= 1) {
      int   lo = __shfl_up(li, d);
      float a1 = __shfl_up(ml, d);
      float a2 = __shfl_up(mu, d);
      bool same = (lane >= d) && (lo == li);
      ml += same ? a1 : 0.f;
      mu += same ? a2 : 0.f;
    }
    int ln = __shfl_down(li, 1);
    bool runend = (lane == 63) ? last : (ln != li);
    if (runend) { g1[li] = ml; g2[li + 1] = mu; }
    if (!last) {
      cml = __shfl(ml, 63);
      cmu = __shfl(mu, 63);
      ck  = __shfl(li, 63);
    }
  }
}

// ---------- convolution: uniform-b128 kernel taps + batched q reads ----------
// kvs[i] = kv[ML+i] for i<=T, 0 for T<i<W (W mult of 4, 16B-aligned base).
// q claimed [LQ,HQ]; guards [LQ-W+1,LQ) and (HQ,HQ+T] pre-zeroed.
__device__ __forceinline__ void conv_pad2(const float* __restrict__ q,
                                          float* __restrict__ qn,
                                          const float* __restrict__ kvs,
                                          int ML, int W, int T,
                                          int LQ, int HQ, int lane)
{
  const int Lout = LQ + ML, Hout = HQ + ML + T;
  for (int J = Lout + lane; J <= Hout; J += 64) {
    const float* qp = q + (J - ML);
    float acc = 0.f;
    for (int c = 0; c < W; c += 4) {
      float4 k4 = *(const float4*)(kvs + c);   // uniform address -> broadcast
      acc = fmaf(k4.x, qp[-c],     acc);
      acc = fmaf(k4.y, qp[-c - 1], acc);
      acc = fmaf(k4.z, qp[-c - 2], acc);
      acc = fmaf(k4.w, qp[-c - 3], acc);
    }
    qn[J] = acc;
  }
}

// =================== Kernel 1: hypernet MLPs (+ inline dtype detect) ========
template<int BF>
__device__ __forceinline__ float ldt(const void* p, int i) {
  if (BF) return bf2f(((const u16*)p)[i]);
  return ((const float*)p)[i];
}

template<int BF>
__device__ __forceinline__ float dot128_t(const void* w, int row, const float* s) {
  float acc = 0.f;
  if (BF) {
    const uint4* p = (const uint4*)((const u16*)w + row * 128);
#pragma unroll
    for (int i = 0; i < 16; ++i) {
      uint4 v = p[i];
      int b = i * 8;
      acc = fmaf(bflo(v.x), s[b + 0], acc); acc = fmaf(bfhi(v.x), s[b + 1], acc);
      acc = fmaf(bflo(v.y), s[b + 2], acc); acc = fmaf(bfhi(v.y), s[b + 3], acc);
      acc = fmaf(bflo(v.z), s[b + 4], acc); acc = fmaf(bfhi(v.z), s[b + 5], acc);
      acc = fmaf(bflo(v.w), s[b + 6], acc); acc = fmaf(bfhi(v.w), s[b + 7], acc);
    }
  } else {
    const float4* p = (const float4*)((const float*)w + row * 128);
#pragma unroll
    for (int i = 0; i < 32; ++i) {
      float4 v = p[i];
      int b = i * 4;
      acc = fmaf(v.x, s[b + 0], acc); acc = fmaf(v.y, s[b + 1], acc);
      acc = fmaf(v.z, s[b + 2], acc); acc = fmaf(v.w, s[b + 3], acc);
    }
  }
  return acc;
}

template<int BF>
__device__ __forceinline__ float dot64_t(const void* w, int row, const float* h) {
  float acc = 0.f;
  if (BF) {
    const uint4* p = (const uint4*)((const u16*)w + row * 64);
#pragma unroll
    for (int i = 0; i < 8; ++i) {
      uint4 v = p[i];
      int b = i * 8;
      acc = fmaf(bflo(v.x), h[b + 0], acc); acc = fmaf(bfhi(v.x), h[b + 1], acc);
      acc = fmaf(bflo(v.y), h[b + 2], acc); acc = fmaf(bfhi(v.y), h[b + 3], acc);
      acc = fmaf(bflo(v.z), h[b + 4], acc); acc = fmaf(bfhi(v.z), h[b + 5], acc);
      acc = fmaf(bflo(v.w), h[b + 6], acc); acc = fmaf(bfhi(v.w), h[b + 7], acc);
    }
  } else {
    const float4* p = (const float4*)((const float*)w + row * 64);
#pragma unroll
    for (int i = 0; i < 16; ++i) {
      float4 v = p[i];
      int b = i * 4;
      acc = fmaf(v.x, h[b + 0], acc); acc = fmaf(v.y, h[b + 1], acc);
      acc = fmaf(v.z, h[b + 2], acc); acc = fmaf(v.w, h[b + 3], acc);
    }
  }
  return acc;
}

template<int BF>
__device__ __forceinline__ void mlp_body(
    const void* states,
    const void* hw1_w1, const void* hw1_b1, const void* hw1_w2, const void* hw1_b2,
    const void* hb1_w,  const void* hb1_b,
    const void* hwf_w1, const void* hwf_b1, const void* hwf_w2, const void* hwf_b2,
    const void* v_w1,   const void* v_b1,   const void* v_w2,   const void* v_b2,
    float* w1_ws, float* b1_ws, float* wf_ws, float* v_ws,
    int n, int tid, float* s, float* h1, float* hf, float* vh)
{
  s[tid]      = ldt<BF>(states, n * 128 + tid);
  s[tid + 64] = ldt<BF>(states, n * 128 + 64 + tid);
  __syncthreads();

  h1[tid] = fmaxf(dot128_t<BF>(hw1_w1, tid, s) + ldt<BF>(hw1_b1, tid), 0.f);
  hf[tid] = fmaxf(dot128_t<BF>(hwf_w1, tid, s) + ldt<BF>(hwf_b1, tid), 0.f);
  if (tid < 32) {
    vh[tid] = fmaxf(dot128_t<BF>(v_w1, tid, s) + ldt<BF>(v_b1, tid), 0.f);
    b1_ws[n * 32 + tid] = dot128_t<BF>(hb1_w, tid, s) + ldt<BF>(hb1_b, tid);
  }
  __syncthreads();

#pragma unroll
  for (int k = 0; k < 4; ++k) {
    int o = tid + 64 * k;
    w1_ws[n * 256 + o] = fabsf(dot64_t<BF>(hw1_w2, o, h1) + ldt<BF>(hw1_b2, o));
  }
  if (tid < 32)
    wf_ws[n * 32 + tid] = fabsf(dot64_t<BF>(hwf_w2, tid, hf) + ldt<BF>(hwf_b2, tid));
  if (tid == 0) {
    float acc = ldt<BF>(v_b2, 0);
    for (int e = 0; e < 32; ++e) acc = fmaf(ldt<BF>(v_w2, e), vh[e], acc);
    v_ws[n] = acc;
  }
}

__global__ __launch_bounds__(64) void k_mlp(
    const void* __restrict__ states,
    const void* __restrict__ hw1_w1, const void* __restrict__ hw1_b1,
    const void* __restrict__ hw1_w2, const void* __restrict__ hw1_b2,
    const void* __restrict__ hb1_w,  const void* __restrict__ hb1_b,
    const void* __restrict__ hwf_w1, const void* __restrict__ hwf_b1,
    const void* __restrict__ hwf_w2, const void* __restrict__ hwf_b2,
    const void* __restrict__ v_w1,   const void* __restrict__ v_b1,
    const void* __restrict__ v_w2,   const void* __restrict__ v_b2,
    float* __restrict__ w1_ws, float* __restrict__ b1_ws,
    float* __restrict__ wf_ws, float* __restrict__ v_ws,
    int* __restrict__ flag)
{
  __shared__ float s[128];
  __shared__ float h1[64];
  __shared__ float hf[64];
  __shared__ float vh[32];
  const int n = blockIdx.x;
  const int tid = threadIdx.x;

  // inline dtype detect on first 128 u16 words of states (~N(0,1), no zeros):
  // bf16 words ~all have plausible exponent; fp32-as-u16 ~ half. thr 104.
  const u16* sr = (const u16*)states;
  unsigned int e0 = (sr[tid] >> 7) & 0xFF;
  unsigned int e1 = (sr[tid + 64] >> 7) & 0xFF;
  unsigned long long bl0 = __ballot(e0 >= 97 && e0 <= 141);
  unsigned long long bl1 = __ballot(e1 >= 97 && e1 <= 141);
  int bf = (__popcll(bl0) + __popcll(bl1) >= 104) ? 1 : 0;
  if (tid == 0) *flag = bf;   // all blocks write same value (benign)

  if (bf)
    mlp_body<1>(states, hw1_w1, hw1_b1, hw1_w2, hw1_b2, hb1_w, hb1_b,
                hwf_w1, hwf_b1, hwf_w2, hwf_b2, v_w1, v_b1, v_w2, v_b2,
                w1_ws, b1_ws, wf_ws, v_ws, n, tid, s, h1, hf, vh);
  else
    mlp_body<0>(states, hw1_w1, hw1_b1, hw1_w2, hw1_b2, hb1_w, hb1_b,
                hwf_w1, hwf_b1, hwf_w2, hwf_b2, v_w1, v_b1, v_w2, v_b2,
                w1_ws, b1_ws, wf_ws, v_ws, n, tid, s, h1, hf, vh);
}

// ======= Kernel 2: 2 tasks per 128-thread block, one wave per task,
//         atomic-free scan projections + uniform-b128 conv taps =======
__global__ __launch_bounds__(128) void k_perembed(
    const void* __restrict__ aq,          // (1024, 8, 51)
    const float* __restrict__ w1_ws, const float* __restrict__ b1_ws,
    const float* __restrict__ wf_ws, float* __restrict__ xw_ws,
    const int* __restrict__ flag)
{
  __shared__ __align__(16) float Ab[2][520];
  __shared__ __align__(16) float Bb[2][520];
  __shared__ __align__(16) float kvsb[2][56];
  __shared__ float gAb[2][53];
  __shared__ float gBb[2][54];

  const int w    = threadIdx.x >> 6;
  const int lane = threadIdx.x & 63;
  const int task = blockIdx.x * 2 + w;
  const int n = task >> 5;
  const int e = task & 31;
  const int bf = *flag;

  float* A   = Ab[w];
  float* B   = Bb[w];
  float* kvs = kvsb[w];
  float* gA  = gAb[w];
  float* gB  = gBb[w];

  // ---- prefetch: 8 agent probs, w1 row, scalars ----
  float pv[8];
  if (bf) {
    const u16* p = (const u16*)aq + n * 408 + lane;
#pragma unroll
    for (int a = 0; a < 8; ++a) pv[a] = (lane < 51) ? bf2f(p[a * 51]) : 0.f;
  } else {
    const float* p = (const float*)aq + n * 408 + lane;
#pragma unroll
    for (int a = 0; a < 8; ++a) pv[a] = (lane < 51) ? p[a * 51] : 0.f;
  }
  float wreg = (lane < 8) ? w1_ws[n * 256 + e * 8 + lane] : 0.f;
  float b1v  = b1_ws[n * 32 + e];
  float wfv  = wf_ws[n * 32 + e];

  // ---- seed: agent 0 projection (scan) -> A at base 64 ----
  float wv0 = __shfl(wreg, 0);
  int ML0, MH0;
  proj_bounds(wv0, ML0, MH0);
  {
    float pa = pv[0];
    proj_scan(gA, gB, 51, lane, [&](int t, bool act, float& sup, float& p) {
      sup = (-10.0f + 0.4f * (float)t) * wv0;
      p = act ? pa : 0.f;                 // single chunk: lane == t
    });
  }
  if (lane <= MH0 - ML0)
    A[64 + ML0 + lane] = gA[ML0 + lane] + gB[ML0 + lane];
  WAVE_SYNC();

  int LQ = 64 + ML0, HQ = 64 + MH0;
  float* q = A;
  float* qn = B;
#pragma unroll
  for (int a = 1; a < 8; ++a) {
    float wv = __shfl(wreg, a);
    int ML, MH;
    proj_bounds(wv, ML, MH);
    int T = MH - ML;
    int W = (T + 4) & ~3;                 // >= T+1, mult of 4
    float pa = pv[a];
    proj_scan(gA, gB, 51, lane, [&](int t, bool act, float& sup, float& p) {
      sup = (-10.0f + 0.4f * (float)t) * wv;
      p = act ? pa : 0.f;
    });
    // combine kernel into aligned padded kvs; zero q guards
    if (lane < W)     kvs[lane] = (lane <= T) ? (gA[ML + lane] + gB[ML + lane]) : 0.f;
    if (lane < W - 1) q[LQ - 1 - lane] = 0.f;
    if (lane < T)     q[HQ + 1 + lane] = 0.f;
    WAVE_SYNC();
    conv_pad2(q, qn, kvs, ML, W, T, LQ, HQ, lane);
    WAVE_SYNC();
    LQ += ML; HQ += MH;
    float* t_ = q; q = qn; qn = t_;
  }

  // ---- elu projection (chunked scan over claimed span) ----
  {
    int span = HQ - LQ + 1;
    int LQl = LQ;
    const float* qf = q;
    proj_scan(gA, gB, span, lane, [&](int t, bool act, float& sup, float& p) {
      int tg = (LQl - 64) + t;            // grid index in [0,400]
      float raw = (-80.0f + 0.4f * (float)tg) + b1v;
      sup = (raw > 0.f) ? raw : expm1f(raw);
      p = act ? qf[LQl + t] : 0.f;
    });
  }
  WAVE_SYNC();

  // ---- wf projection: x2 (in gA/gB) -> xw ----
  float x2v = (lane < 51) ? (gA[lane] + gB[lane]) : 0.f;
  WAVE_SYNC();                            // fence: read before re-zero
  int MLf, MHf;
  proj_bounds(wfv, MLf, MHf);
  proj_scan(gA, gB, 51, lane, [&](int t, bool act, float& sup, float& p) {
    sup = (-10.0f + 0.4f * (float)t) * wfv;
    p = act ? x2v : 0.f;                  // single chunk: lane == t
  });
  WAVE_SYNC();
  if (lane <= MHf - MLf)
    xw_ws[task * 51 + MLf + lane] = gA[MLf + lane] + gB[MLf + lane];
}

// ====== Kernel 3: one wave per sample, 31-conv chain + scan projection ======
__global__ __launch_bounds__(64) void k_final(
    const float* __restrict__ xw_ws, const float* __restrict__ wf_ws,
    const float* __restrict__ v_ws,
    void* __restrict__ out, const int* __restrict__ flag)
{
  __shared__ __align__(16) float A[1720];
  __shared__ __align__(16) float B[1720];
  __shared__ __align__(16) float kvs[56];
  __shared__ float gA[53];
  __shared__ float gB[54];

  const int n    = blockIdx.x;
  const int lane = threadIdx.x;
  const int bf   = *flag;

  float wfreg = (lane < 32) ? wf_ws[n * 32 + lane] : 0.f;
  float vv    = v_ws[n];

  // e = 0 seed
  float wv0 = __shfl(wfreg, 0);
  int ML0, MH0;
  proj_bounds(wv0, ML0, MH0);
  if (lane <= MH0 - ML0)
    A[64 + ML0 + lane] = xw_ws[(n * 32 + 0) * 51 + ML0 + lane];

  int LQ = 64 + ML0, HQ = 64 + MH0;
  float* q = A;
  float* qn = B;

  // prefetch e=1 kernel row
  int MLn, MHn;
  { float wvn = __shfl(wfreg, 1); proj_bounds(wvn, MLn, MHn); }
  float nv = (lane <= MHn - MLn) ? xw_ws[(n * 32 + 1) * 51 + MLn + lane] : 0.f;

  for (int e = 1; e < 32; ++e) {
    int ML = MLn, MH = MHn;
    int T = MH - ML;
    int W = (T + 4) & ~3;
    if (lane < W)     kvs[lane] = (lane <= T) ? nv : 0.f;
    if (lane < W - 1) q[LQ - 1 - lane] = 0.f;
    if (lane < T)     q[HQ + 1 + lane] = 0.f;
    if (e < 31) {                         // next row load overlaps conv
      float wvn = __shfl(wfreg, e + 1);
      proj_bounds(wvn, MLn, MHn);
      nv = (lane <= MHn - MLn) ? xw_ws[(n * 32 + e + 1) * 51 + MLn + lane] : 0.f;
    }
    WAVE_SYNC();
    conv_pad2(q, qn, kvs, ML, W, T, LQ, HQ, lane);
    WAVE_SYNC();
    LQ += ML; HQ += MH;
    float* t_ = q; q = qn; qn = t_;
  }

  // final projection (chunked scan; clip masses handled naturally)
  {
    int span = HQ - LQ + 1;
    int LQl = LQ;
    const float* qf = q;
    proj_scan(gA, gB, span, lane, [&](int t, bool act, float& sup, float& p) {
      int tg = (LQl - 64) + t;            // grid index in [0,1600]
      sup = (-320.0f + 0.4f * (float)tg) + vv;
      p = act ? qf[LQl + t] : 0.f;
    });
  }
  WAVE_SYNC();

  if (lane < 51) {
    float o = gA[lane] + gB[lane];
    if (bf) ((u16*)out)[n * 51 + lane] = f2bf(o);
    else    ((float*)out)[n * 51 + lane] = o;
  }
}

// =========================== launcher ===========================
extern "C" void kernel_launch(void* const* d_in, const int* in_sizes, int n_in,
                              void* d_out, int out_size, void* d_ws, size_t ws_size,
                              hipStream_t stream)
{
  float* ws    = (float*)d_ws;
  float* w1_ws = ws;                       // 1024*256
  float* b1_ws = w1_ws + 1024 * 256;       // 1024*32
  float* wf_ws = b1_ws + 1024 * 32;        // 1024*32
  float* v_ws  = wf_ws + 1024 * 32;        // 1024
  float* xw_ws = v_ws  + 1024;             // 1024*32*51
  int*   flag  = (int*)(xw_ws + 1024 * 32 * 51);

  k_mlp<<<1024, 64, 0, stream>>>(d_in[1],
      d_in[2], d_in[3], d_in[4], d_in[5], d_in[6], d_in[7],
      d_in[8], d_in[9], d_in[10], d_in[11], d_in[12], d_in[13],
      d_in[14], d_in[15],
      w1_ws, b1_ws, wf_ws, v_ws, flag);

  k_perembed<<<16384, 128, 0, stream>>>(d_in[0], w1_ws, b1_ws, wf_ws, xw_ws, flag);

  k_final<<<1024, 64, 0, stream>>>(xw_ws, wf_ws, v_ws, d_out, flag);
}

// Round 8
// 250.682 us; speedup vs baseline: 2.0828x; 1.0779x over previous
//
#include <hip/hip_runtime.h>
#include <hip/hip_bf16.h>
#include <math.h>

typedef unsigned short u16;

// Compiler memory fence + drain of this wave's LDS ops. Each task's LDS region
// is touched by exactly ONE wave; same-wave DS ops execute in order.
#define WAVE_SYNC() asm volatile("s_waitcnt lgkmcnt(0)" ::: "memory")

// ---------- dtype helpers ----------
__device__ __forceinline__ float bf2f(u16 u) {
  union { unsigned int i; float f; } c;
  c.i = ((unsigned int)u) << 16;
  return c.f;
}
__device__ __forceinline__ float bflo(unsigned int u) {
  union { unsigned int i; float f; } c; c.i = u << 16; return c.f;
}
__device__ __forceinline__ float bfhi(unsigned int u) {
  union { unsigned int i; float f; } c; c.i = u & 0xffff0000u; return c.f;
}
__device__ __forceinline__ u16 f2bf(float f) {
  union { float f; unsigned int i; } c;
  c.f = f;
  unsigned int x = c.i;
  unsigned int r = (x + 0x7fffu + ((x >> 16) & 1u)) >> 16; // RNE
  return (u16)r;
}

// Destination-bin bounds for proj of supports (-10+0.4t)*wv, t=0..50, wv>=0.
// Endpoints use IDENTICAL float ops as the projection => conservative-exact.
__device__ __forceinline__ void proj_bounds(float wv, int& ML, int& MH) {
  float smin = (-10.0f + 0.4f * 0.0f)  * wv;
  float smax = (-10.0f + 0.4f * 50.0f) * wv;
  float bmin = (fminf(fmaxf(smin, -10.0f), 10.0f) + 10.0f) / 0.4f;
  float bmax = (fminf(fmaxf(smax, -10.0f), 10.0f) + 10.0f) / 0.4f;
  ML = (int)floorf(bmin);
  MH = (int)ceilf(bmax);
}

// ---------- atomic-free projection via segmented scan ----------
// Keys l(t)=floor(b(t)) are monotone in t. Segmented inclusive scan over
// lanes; run-end lanes store g1[l]=sum(ml), g2[l+1]=sum(mu) (collision-free).
// Bin j = g1[j]+g2[j]. Chunked with cross-chunk run carry for span>64.
template<typename SUPP>
__device__ __forceinline__ void proj_scan(float* __restrict__ g1,
                                          float* __restrict__ g2,
                                          int span, int lane, SUPP supp)
{
  if (lane < 52) g1[lane] = 0.f;
  if (lane < 53) g2[lane] = 0.f;
  float cml = 0.f, cmu = 0.f;
  int ck = -1;
  for (int base = 0; base < span; base += 64) {
    int t = base + lane;
    bool act = (t < span);
    int tc = act ? t : (span - 1);
    float sup, p;
    supp(tc, act, sup, p);
    float c  = fminf(fmaxf(sup, -10.0f), 10.0f);
    float b  = (c + 10.0f) / 0.4f;
    float l  = floorf(b);
    float u  = ceilf(b);
    float eq = (u == l) ? 1.0f : 0.0f;
    float ml = p * (u - b + eq);
    float mu = p * (b - l);
    int   li = (int)l;
    bool last = (base + 64 >= span);
    if (lane == 0 && ck >= 0) {
      if (ck == li) { ml += cml; mu += cmu; }
      else          { g1[ck] = cml; g2[ck + 1] = cmu; }
    }
#pragma unroll
    for (int d = 1; d < 64; d <<= 1) {
      int   lo = __shfl_up(li, d);
      float a1 = __shfl_up(ml, d);
      float a2 = __shfl_up(mu, d);
      bool same = (lane >= d) && (lo == li);
      ml += same ? a1 : 0.f;
      mu += same ? a2 : 0.f;
    }
    int ln = __shfl_down(li, 1);
    bool runend = (lane == 63) ? last : (ln != li);
    if (runend) { g1[li] = ml; g2[li + 1] = mu; }
    if (!last) {
      cml = __shfl(ml, 63);
      cmu = __shfl(mu, 63);
      ck  = __shfl(li, 63);
    }
  }
}

// ---------- convolution: uniform-b128 kernel taps + batched q reads ----------
// kvs[i] = kv[ML+i] for i<=T, 0 for T<i<W (W mult of 4, 16B-aligned base).
// q claimed [LQ,HQ]; guards [LQ-W+1,LQ) and (HQ,HQ+T] pre-zeroed.
__device__ __forceinline__ void conv_pad2(const float* __restrict__ q,
                                          float* __restrict__ qn,
                                          const float* __restrict__ kvs,
                                          int ML, int W, int T,
                                          int LQ, int HQ, int tid, int nthr)
{
  const int Lout = LQ + ML, Hout = HQ + ML + T;
  for (int J = Lout + tid; J <= Hout; J += nthr) {
    const float* qp = q + (J - ML);
    float acc = 0.f;
    for (int c = 0; c < W; c += 4) {
      float4 k4 = *(const float4*)(kvs + c);   // uniform address -> broadcast
      acc = fmaf(k4.x, qp[-c],     acc);
      acc = fmaf(k4.y, qp[-c - 1], acc);
      acc = fmaf(k4.z, qp[-c - 2], acc);
      acc = fmaf(k4.w, qp[-c - 3], acc);
    }
    qn[J] = acc;
  }
}

// =================== Kernel 1: hypernet MLPs (+ inline dtype detect) ========
template<int BF>
__device__ __forceinline__ float ldt(const void* p, int i) {
  if (BF) return bf2f(((const u16*)p)[i]);
  return ((const float*)p)[i];
}

template<int BF>
__device__ __forceinline__ float dot128_t(const void* w, int row, const float* s) {
  float acc = 0.f;
  if (BF) {
    const uint4* p = (const uint4*)((const u16*)w + row * 128);
#pragma unroll
    for (int i = 0; i < 16; ++i) {
      uint4 v = p[i];
      int b = i * 8;
      acc = fmaf(bflo(v.x), s[b + 0], acc); acc = fmaf(bfhi(v.x), s[b + 1], acc);
      acc = fmaf(bflo(v.y), s[b + 2], acc); acc = fmaf(bfhi(v.y), s[b + 3], acc);
      acc = fmaf(bflo(v.z), s[b + 4], acc); acc = fmaf(bfhi(v.z), s[b + 5], acc);
      acc = fmaf(bflo(v.w), s[b + 6], acc); acc = fmaf(bfhi(v.w), s[b + 7], acc);
    }
  } else {
    const float4* p = (const float4*)((const float*)w + row * 128);
#pragma unroll
    for (int i = 0; i < 32; ++i) {
      float4 v = p[i];
      int b = i * 4;
      acc = fmaf(v.x, s[b + 0], acc); acc = fmaf(v.y, s[b + 1], acc);
      acc = fmaf(v.z, s[b + 2], acc); acc = fmaf(v.w, s[b + 3], acc);
    }
  }
  return acc;
}

template<int BF>
__device__ __forceinline__ float dot64_t(const void* w, int row, const float* h) {
  float acc = 0.f;
  if (BF) {
    const uint4* p = (const uint4*)((const u16*)w + row * 64);
#pragma unroll
    for (int i = 0; i < 8; ++i) {
      uint4 v = p[i];
      int b = i * 8;
      acc = fmaf(bflo(v.x), h[b + 0], acc); acc = fmaf(bfhi(v.x), h[b + 1], acc);
      acc = fmaf(bflo(v.y), h[b + 2], acc); acc = fmaf(bfhi(v.y), h[b + 3], acc);
      acc = fmaf(bflo(v.z), h[b + 4], acc); acc = fmaf(bfhi(v.z), h[b + 5], acc);
      acc = fmaf(bflo(v.w), h[b + 6], acc); acc = fmaf(bfhi(v.w), h[b + 7], acc);
    }
  } else {
    const float4* p = (const float4*)((const float*)w + row * 64);
#pragma unroll
    for (int i = 0; i < 16; ++i) {
      float4 v = p[i];
      int b = i * 4;
      acc = fmaf(v.x, h[b + 0], acc); acc = fmaf(v.y, h[b + 1], acc);
      acc = fmaf(v.z, h[b + 2], acc); acc = fmaf(v.w, h[b + 3], acc);
    }
  }
  return acc;
}

template<int BF>
__device__ __forceinline__ void mlp_body(
    const void* states,
    const void* hw1_w1, const void* hw1_b1, const void* hw1_w2, const void* hw1_b2,
    const void* hb1_w,  const void* hb1_b,
    const void* hwf_w1, const void* hwf_b1, const void* hwf_w2, const void* hwf_b2,
    const void* v_w1,   const void* v_b1,   const void* v_w2,   const void* v_b2,
    float* w1_ws, float* b1_ws, float* wf_ws, float* v_ws,
    int n, int tid, float* s, float* h1, float* hf, float* vh)
{
  s[tid]      = ldt<BF>(states, n * 128 + tid);
  s[tid + 64] = ldt<BF>(states, n * 128 + 64 + tid);
  __syncthreads();

  h1[tid] = fmaxf(dot128_t<BF>(hw1_w1, tid, s) + ldt<BF>(hw1_b1, tid), 0.f);
  hf[tid] = fmaxf(dot128_t<BF>(hwf_w1, tid, s) + ldt<BF>(hwf_b1, tid), 0.f);
  if (tid < 32) {
    vh[tid] = fmaxf(dot128_t<BF>(v_w1, tid, s) + ldt<BF>(v_b1, tid), 0.f);
    b1_ws[n * 32 + tid] = dot128_t<BF>(hb1_w, tid, s) + ldt<BF>(hb1_b, tid);
  }
  __syncthreads();

#pragma unroll
  for (int k = 0; k < 4; ++k) {
    int o = tid + 64 * k;
    w1_ws[n * 256 + o] = fabsf(dot64_t<BF>(hw1_w2, o, h1) + ldt<BF>(hw1_b2, o));
  }
  if (tid < 32)
    wf_ws[n * 32 + tid] = fabsf(dot64_t<BF>(hwf_w2, tid, hf) + ldt<BF>(hwf_b2, tid));
  if (tid == 0) {
    float acc = ldt<BF>(v_b2, 0);
    for (int e = 0; e < 32; ++e) acc = fmaf(ldt<BF>(v_w2, e), vh[e], acc);
    v_ws[n] = acc;
  }
}

__global__ __launch_bounds__(64) void k_mlp(
    const void* __restrict__ states,
    const void* __restrict__ hw1_w1, const void* __restrict__ hw1_b1,
    const void* __restrict__ hw1_w2, const void* __restrict__ hw1_b2,
    const void* __restrict__ hb1_w,  const void* __restrict__ hb1_b,
    const void* __restrict__ hwf_w1, const void* __restrict__ hwf_b1,
    const void* __restrict__ hwf_w2, const void* __restrict__ hwf_b2,
    const void* __restrict__ v_w1,   const void* __restrict__ v_b1,
    const void* __restrict__ v_w2,   const void* __restrict__ v_b2,
    float* __restrict__ w1_ws, float* __restrict__ b1_ws,
    float* __restrict__ wf_ws, float* __restrict__ v_ws,
    int* __restrict__ flag)
{
  __shared__ float s[128];
  __shared__ float h1[64];
  __shared__ float hf[64];
  __shared__ float vh[32];
  const int n = blockIdx.x;
  const int tid = threadIdx.x;

  // inline dtype detect on first 128 u16 words of states (~N(0,1), no zeros)
  const u16* sr = (const u16*)states;
  unsigned int e0 = (sr[tid] >> 7) & 0xFF;
  unsigned int e1 = (sr[tid + 64] >> 7) & 0xFF;
  unsigned long long bl0 = __ballot(e0 >= 97 && e0 <= 141);
  unsigned long long bl1 = __ballot(e1 >= 97 && e1 <= 141);
  int bf = (__popcll(bl0) + __popcll(bl1) >= 104) ? 1 : 0;
  if (tid == 0) *flag = bf;   // all blocks write same value (benign)

  if (bf)
    mlp_body<1>(states, hw1_w1, hw1_b1, hw1_w2, hw1_b2, hb1_w, hb1_b,
                hwf_w1, hwf_b1, hwf_w2, hwf_b2, v_w1, v_b1, v_w2, v_b2,
                w1_ws, b1_ws, wf_ws, v_ws, n, tid, s, h1, hf, vh);
  else
    mlp_body<0>(states, hw1_w1, hw1_b1, hw1_w2, hw1_b2, hb1_w, hb1_b,
                hwf_w1, hwf_b1, hwf_w2, hwf_b2, v_w1, v_b1, v_w2, v_b2,
                w1_ws, b1_ws, wf_ws, v_ws, n, tid, s, h1, hf, vh);
}

// ======= Kernel 2: 2 tasks per 128-thread block, one wave per task,
//         atomic-free scan projections + uniform-b128 conv taps =======
__global__ __launch_bounds__(128) void k_perembed(
    const void* __restrict__ aq,          // (1024, 8, 51)
    const float* __restrict__ w1_ws, const float* __restrict__ b1_ws,
    const float* __restrict__ wf_ws, float* __restrict__ xw_ws,
    const int* __restrict__ flag)
{
  __shared__ __align__(16) float Ab[2][520];
  __shared__ __align__(16) float Bb[2][520];
  __shared__ __align__(16) float kvsb[2][56];
  __shared__ float gAb[2][53];
  __shared__ float gBb[2][54];

  const int w    = threadIdx.x >> 6;
  const int lane = threadIdx.x & 63;
  const int task = blockIdx.x * 2 + w;
  const int n = task >> 5;
  const int e = task & 31;
  const int bf = *flag;

  float* A   = Ab[w];
  float* B   = Bb[w];
  float* kvs = kvsb[w];
  float* gA  = gAb[w];
  float* gB  = gBb[w];

  // ---- prefetch: 8 agent probs, w1 row, scalars ----
  float pv[8];
  if (bf) {
    const u16* p = (const u16*)aq + n * 408 + lane;
#pragma unroll
    for (int a = 0; a < 8; ++a) pv[a] = (lane < 51) ? bf2f(p[a * 51]) : 0.f;
  } else {
    const float* p = (const float*)aq + n * 408 + lane;
#pragma unroll
    for (int a = 0; a < 8; ++a) pv[a] = (lane < 51) ? p[a * 51] : 0.f;
  }
  float wreg = (lane < 8) ? w1_ws[n * 256 + e * 8 + lane] : 0.f;
  float b1v  = b1_ws[n * 32 + e];
  float wfv  = wf_ws[n * 32 + e];

  // ---- seed: agent 0 projection (scan) -> A at base 64 ----
  float wv0 = __shfl(wreg, 0);
  int ML0, MH0;
  proj_bounds(wv0, ML0, MH0);
  {
    float pa = pv[0];
    proj_scan(gA, gB, 51, lane, [&](int t, bool act, float& sup, float& p) {
      sup = (-10.0f + 0.4f * (float)t) * wv0;
      p = act ? pa : 0.f;
    });
  }
  if (lane <= MH0 - ML0)
    A[64 + ML0 + lane] = gA[ML0 + lane] + gB[ML0 + lane];
  WAVE_SYNC();

  int LQ = 64 + ML0, HQ = 64 + MH0;
  float* q = A;
  float* qn = B;
#pragma unroll
  for (int a = 1; a < 8; ++a) {
    float wv = __shfl(wreg, a);
    int ML, MH;
    proj_bounds(wv, ML, MH);
    int T = MH - ML;
    int W = (T + 4) & ~3;                 // >= T+1, mult of 4
    float pa = pv[a];
    proj_scan(gA, gB, 51, lane, [&](int t, bool act, float& sup, float& p) {
      sup = (-10.0f + 0.4f * (float)t) * wv;
      p = act ? pa : 0.f;
    });
    if (lane < W)     kvs[lane] = (lane <= T) ? (gA[ML + lane] + gB[ML + lane]) : 0.f;
    if (lane < W - 1) q[LQ - 1 - lane] = 0.f;
    if (lane < T)     q[HQ + 1 + lane] = 0.f;
    WAVE_SYNC();
    conv_pad2(q, qn, kvs, ML, W, T, LQ, HQ, lane, 64);
    WAVE_SYNC();
    LQ += ML; HQ += MH;
    float* t_ = q; q = qn; qn = t_;
  }

  // ---- elu projection (chunked scan over claimed span) ----
  {
    int span = HQ - LQ + 1;
    int LQl = LQ;
    const float* qf = q;
    proj_scan(gA, gB, span, lane, [&](int t, bool act, float& sup, float& p) {
      int tg = (LQl - 64) + t;            // grid index in [0,400]
      float raw = (-80.0f + 0.4f * (float)tg) + b1v;
      sup = (raw > 0.f) ? raw : expm1f(raw);
      p = act ? qf[LQl + t] : 0.f;
    });
  }
  WAVE_SYNC();

  // ---- wf projection: x2 (in gA/gB) -> xw ----
  float x2v = (lane < 51) ? (gA[lane] + gB[lane]) : 0.f;
  WAVE_SYNC();                            // fence: read before re-zero
  int MLf, MHf;
  proj_bounds(wfv, MLf, MHf);
  proj_scan(gA, gB, 51, lane, [&](int t, bool act, float& sup, float& p) {
    sup = (-10.0f + 0.4f * (float)t) * wfv;
    p = act ? x2v : 0.f;
  });
  WAVE_SYNC();
  if (lane <= MHf - MLf)
    xw_ws[task * 51 + MLf + lane] = gA[MLf + lane] + gB[MLf + lane];
}

// ====== Kernel 3: 256 threads per sample — each conv split across 4 waves ====
__global__ __launch_bounds__(256) void k_final(
    const float* __restrict__ xw_ws, const float* __restrict__ wf_ws,
    const float* __restrict__ v_ws,
    void* __restrict__ out, const int* __restrict__ flag)
{
  __shared__ __align__(16) float A[1720];
  __shared__ __align__(16) float B[1720];
  __shared__ __align__(16) float kvs[56];
  __shared__ float gA[53];
  __shared__ float gB[54];

  const int n    = blockIdx.x;
  const int tid  = threadIdx.x;
  const int lane = tid & 63;
  const int bf   = *flag;

  // every wave loads wf row (lane<32) so per-wave shuffles agree block-wide
  float wfreg = (lane < 32) ? wf_ws[n * 32 + lane] : 0.f;
  float vv    = v_ws[n];

  // e = 0 seed
  float wv0 = __shfl(wfreg, 0);
  int ML0, MH0;
  proj_bounds(wv0, ML0, MH0);
  if (tid <= MH0 - ML0)
    A[64 + ML0 + tid] = xw_ws[(n * 32 + 0) * 51 + ML0 + tid];

  int LQ = 64 + ML0, HQ = 64 + MH0;
  float* q = A;
  float* qn = B;

  // prefetch e=1 kernel row (wave 0's tid<51 holds it)
  int MLn, MHn;
  { float wvn = __shfl(wfreg, 1); proj_bounds(wvn, MLn, MHn); }
  float nv = (tid <= MHn - MLn) ? xw_ws[(n * 32 + 1) * 51 + MLn + tid] : 0.f;

  for (int e = 1; e < 32; ++e) {
    int ML = MLn, MH = MHn;
    int T = MH - ML;
    int W = (T + 4) & ~3;
    if (tid < W)     kvs[tid] = (tid <= T) ? nv : 0.f;
    if (tid < W - 1) q[LQ - 1 - tid] = 0.f;
    if (tid < T)     q[HQ + 1 + tid] = 0.f;
    if (e < 31) {                         // next row load overlaps conv
      float wvn = __shfl(wfreg, e + 1);
      proj_bounds(wvn, MLn, MHn);
      nv = (tid <= MHn - MLn) ? xw_ws[(n * 32 + e + 1) * 51 + MLn + tid] : 0.f;
    }
    __syncthreads();
    conv_pad2(q, qn, kvs, ML, W, T, LQ, HQ, tid, 256);
    __syncthreads();
    LQ += ML; HQ += MH;
    float* t_ = q; q = qn; qn = t_;
  }

  // final projection (wave 0 only; q visible via the loop's last barrier)
  if (tid < 64) {
    int span = HQ - LQ + 1;
    int LQl = LQ;
    const float* qf = q;
    proj_scan(gA, gB, span, lane, [&](int t, bool act, float& sup, float& p) {
      int tg = (LQl - 64) + t;            // grid index in [0,1600]
      sup = (-320.0f + 0.4f * (float)tg) + vv;
      p = act ? qf[LQl + t] : 0.f;
    });
  }
  __syncthreads();

  if (tid < 51) {
    float o = gA[tid] + gB[tid];
    if (bf) ((u16*)out)[n * 51 + tid] = f2bf(o);
    else    ((float*)out)[n * 51 + tid] = o;
  }
}

// =========================== launcher ===========================
extern "C" void kernel_launch(void* const* d_in, const int* in_sizes, int n_in,
                              void* d_out, int out_size, void* d_ws, size_t ws_size,
                              hipStream_t stream)
{
  float* ws    = (float*)d_ws;
  float* w1_ws = ws;                       // 1024*256
  float* b1_ws = w1_ws + 1024 * 256;       // 1024*32
  float* wf_ws = b1_ws + 1024 * 32;        // 1024*32
  float* v_ws  = wf_ws + 1024 * 32;        // 1024
  float* xw_ws = v_ws  + 1024;             // 1024*32*51
  int*   flag  = (int*)(xw_ws + 1024 * 32 * 51);

  k_mlp<<<1024, 64, 0, stream>>>(d_in[1],
      d_in[2], d_in[3], d_in[4], d_in[5], d_in[6], d_in[7],
      d_in[8], d_in[9], d_in[10], d_in[11], d_in[12], d_in[13],
      d_in[14], d_in[15],
      w1_ws, b1_ws, wf_ws, v_ws, flag);

  k_perembed<<<16384, 128, 0, stream>>>(d_in[0], w1_ws, b1_ws, wf_ws, xw_ws, flag);

  k_final<<<1024, 256, 0, stream>>>(xw_ws, wf_ws, v_ws, d_out, flag);
}

// Round 9
// 250.008 us; speedup vs baseline: 2.0884x; 1.0027x over previous
//
#include <hip/hip_runtime.h>
#include <hip/hip_bf16.h>
#include <math.h>

typedef unsigned short u16;

// Compiler memory fence + drain of this wave's LDS ops. Each task's LDS region
// is touched by exactly ONE wave; same-wave DS ops execute in order.
#define WAVE_SYNC() asm volatile("s_waitcnt lgkmcnt(0)" ::: "memory")

// ---------- dtype helpers ----------
__device__ __forceinline__ float bf2f(u16 u) {
  union { unsigned int i; float f; } c;
  c.i = ((unsigned int)u) << 16;
  return c.f;
}
__device__ __forceinline__ float bflo(unsigned int u) {
  union { unsigned int i; float f; } c; c.i = u << 16; return c.f;
}
__device__ __forceinline__ float bfhi(unsigned int u) {
  union { unsigned int i; float f; } c; c.i = u & 0xffff0000u; return c.f;
}
__device__ __forceinline__ u16 f2bf(float f) {
  union { float f; unsigned int i; } c;
  c.f = f;
  unsigned int x = c.i;
  unsigned int r = (x + 0x7fffu + ((x >> 16) & 1u)) >> 16; // RNE
  return (u16)r;
}

// Destination-bin bounds for proj of supports (-10+0.4t)*wv, t=0..50, wv>=0.
// Endpoints use IDENTICAL float ops as the projection => conservative-exact.
__device__ __forceinline__ void proj_bounds(float wv, int& ML, int& MH) {
  float smin = (-10.0f + 0.4f * 0.0f)  * wv;
  float smax = (-10.0f + 0.4f * 50.0f) * wv;
  float bmin = (fminf(fmaxf(smin, -10.0f), 10.0f) + 10.0f) / 0.4f;
  float bmax = (fminf(fmaxf(smax, -10.0f), 10.0f) + 10.0f) / 0.4f;
  ML = (int)floorf(bmin);
  MH = (int)ceilf(bmax);
}

// ---------- atomic-free projection via segmented scan ----------
// Keys l(t)=floor(b(t)) are monotone in t. Segmented inclusive scan over
// lanes; run-end lanes store g1[l]=sum(ml), g2[l+1]=sum(mu) (collision-free).
// Bin j = g1[j]+g2[j]. Chunked with cross-chunk run carry for span>64.
template<typename SUPP>
__device__ __forceinline__ void proj_scan(float* __restrict__ g1,
                                          float* __restrict__ g2,
                                          int span, int lane, SUPP supp)
{
  if (lane < 52) g1[lane] = 0.f;
  if (lane < 53) g2[lane] = 0.f;
  float cml = 0.f, cmu = 0.f;
  int ck = -1;
  for (int base = 0; base < span; base += 64) {
    int t = base + lane;
    bool act = (t < span);
    int tc = act ? t : (span - 1);
    float sup, p;
    supp(tc, act, sup, p);
    float c  = fminf(fmaxf(sup, -10.0f), 10.0f);
    float b  = (c + 10.0f) / 0.4f;
    float l  = floorf(b);
    float u  = ceilf(b);
    float eq = (u == l) ? 1.0f : 0.0f;
    float ml = p * (u - b + eq);
    float mu = p * (b - l);
    int   li = (int)l;
    bool last = (base + 64 >= span);
    if (lane == 0 && ck >= 0) {
      if (ck == li) { ml += cml; mu += cmu; }
      else          { g1[ck] = cml; g2[ck + 1] = cmu; }
    }
#pragma unroll
    for (int d = 1; d < 64; d <<= 1) {
      int   lo = __shfl_up(li, d);
      float a1 = __shfl_up(ml, d);
      float a2 = __shfl_up(mu, d);
      bool same = (lane >= d) && (lo == li);
      ml += same ? a1 : 0.f;
      mu += same ? a2 : 0.f;
    }
    int ln = __shfl_down(li, 1);
    bool runend = (lane == 63) ? last : (ln != li);
    if (runend) { g1[li] = ml; g2[li + 1] = mu; }
    if (!last) {
      cml = __shfl(ml, 63);
      cmu = __shfl(mu, 63);
      ck  = __shfl(li, 63);
    }
  }
}

// ---------- convolution: uniform-b128 kernel taps + batched q reads ----------
// (used by k_perembed; unchanged from R7/R8)
__device__ __forceinline__ void conv_pad2(const float* __restrict__ q,
                                          float* __restrict__ qn,
                                          const float* __restrict__ kvs,
                                          int ML, int W, int T,
                                          int LQ, int HQ, int tid, int nthr)
{
  const int Lout = LQ + ML, Hout = HQ + ML + T;
  for (int J = Lout + tid; J <= Hout; J += nthr) {
    const float* qp = q + (J - ML);
    float acc = 0.f;
    for (int c = 0; c < W; c += 4) {
      float4 k4 = *(const float4*)(kvs + c);   // uniform address -> broadcast
      acc = fmaf(k4.x, qp[-c],     acc);
      acc = fmaf(k4.y, qp[-c - 1], acc);
      acc = fmaf(k4.z, qp[-c - 2], acc);
      acc = fmaf(k4.w, qp[-c - 3], acc);
    }
    qn[J] = acc;
  }
}

// =================== Kernel 1: hypernet MLPs (+ inline dtype detect) ========
template<int BF>
__device__ __forceinline__ float ldt(const void* p, int i) {
  if (BF) return bf2f(((const u16*)p)[i]);
  return ((const float*)p)[i];
}

template<int BF>
__device__ __forceinline__ float dot128_t(const void* w, int row, const float* s) {
  float acc = 0.f;
  if (BF) {
    const uint4* p = (const uint4*)((const u16*)w + row * 128);
#pragma unroll
    for (int i = 0; i < 16; ++i) {
      uint4 v = p[i];
      int b = i * 8;
      acc = fmaf(bflo(v.x), s[b + 0], acc); acc = fmaf(bfhi(v.x), s[b + 1], acc);
      acc = fmaf(bflo(v.y), s[b + 2], acc); acc = fmaf(bfhi(v.y), s[b + 3], acc);
      acc = fmaf(bflo(v.z), s[b + 4], acc); acc = fmaf(bfhi(v.z), s[b + 5], acc);
      acc = fmaf(bflo(v.w), s[b + 6], acc); acc = fmaf(bfhi(v.w), s[b + 7], acc);
    }
  } else {
    const float4* p = (const float4*)((const float*)w + row * 128);
#pragma unroll
    for (int i = 0; i < 32; ++i) {
      float4 v = p[i];
      int b = i * 4;
      acc = fmaf(v.x, s[b + 0], acc); acc = fmaf(v.y, s[b + 1], acc);
      acc = fmaf(v.z, s[b + 2], acc); acc = fmaf(v.w, s[b + 3], acc);
    }
  }
  return acc;
}

template<int BF>
__device__ __forceinline__ float dot64_t(const void* w, int row, const float* h) {
  float acc = 0.f;
  if (BF) {
    const uint4* p = (const uint4*)((const u16*)w + row * 64);
#pragma unroll
    for (int i = 0; i < 8; ++i) {
      uint4 v = p[i];
      int b = i * 8;
      acc = fmaf(bflo(v.x), h[b + 0], acc); acc = fmaf(bfhi(v.x), h[b + 1], acc);
      acc = fmaf(bflo(v.y), h[b + 2], acc); acc = fmaf(bfhi(v.y), h[b + 3], acc);
      acc = fmaf(bflo(v.z), h[b + 4], acc); acc = fmaf(bfhi(v.z), h[b + 5], acc);
      acc = fmaf(bflo(v.w), h[b + 6], acc); acc = fmaf(bfhi(v.w), h[b + 7], acc);
    }
  } else {
    const float4* p = (const float4*)((const float*)w + row * 64);
#pragma unroll
    for (int i = 0; i < 16; ++i) {
      float4 v = p[i];
      int b = i * 4;
      acc = fmaf(v.x, h[b + 0], acc); acc = fmaf(v.y, h[b + 1], acc);
      acc = fmaf(v.z, h[b + 2], acc); acc = fmaf(v.w, h[b + 3], acc);
    }
  }
  return acc;
}

template<int BF>
__device__ __forceinline__ void mlp_body(
    const void* states,
    const void* hw1_w1, const void* hw1_b1, const void* hw1_w2, const void* hw1_b2,
    const void* hb1_w,  const void* hb1_b,
    const void* hwf_w1, const void* hwf_b1, const void* hwf_w2, const void* hwf_b2,
    const void* v_w1,   const void* v_b1,   const void* v_w2,   const void* v_b2,
    float* w1_ws, float* b1_ws, float* wf_ws, float* v_ws,
    int n, int tid, float* s, float* h1, float* hf, float* vh)
{
  s[tid]      = ldt<BF>(states, n * 128 + tid);
  s[tid + 64] = ldt<BF>(states, n * 128 + 64 + tid);
  __syncthreads();

  h1[tid] = fmaxf(dot128_t<BF>(hw1_w1, tid, s) + ldt<BF>(hw1_b1, tid), 0.f);
  hf[tid] = fmaxf(dot128_t<BF>(hwf_w1, tid, s) + ldt<BF>(hwf_b1, tid), 0.f);
  if (tid < 32) {
    vh[tid] = fmaxf(dot128_t<BF>(v_w1, tid, s) + ldt<BF>(v_b1, tid), 0.f);
    b1_ws[n * 32 + tid] = dot128_t<BF>(hb1_w, tid, s) + ldt<BF>(hb1_b, tid);
  }
  __syncthreads();

#pragma unroll
  for (int k = 0; k < 4; ++k) {
    int o = tid + 64 * k;
    w1_ws[n * 256 + o] = fabsf(dot64_t<BF>(hw1_w2, o, h1) + ldt<BF>(hw1_b2, o));
  }
  if (tid < 32)
    wf_ws[n * 32 + tid] = fabsf(dot64_t<BF>(hwf_w2, tid, hf) + ldt<BF>(hwf_b2, tid));
  if (tid == 0) {
    float acc = ldt<BF>(v_b2, 0);
    for (int e = 0; e < 32; ++e) acc = fmaf(ldt<BF>(v_w2, e), vh[e], acc);
    v_ws[n] = acc;
  }
}

__global__ __launch_bounds__(64) void k_mlp(
    const void* __restrict__ states,
    const void* __restrict__ hw1_w1, const void* __restrict__ hw1_b1,
    const void* __restrict__ hw1_w2, const void* __restrict__ hw1_b2,
    const void* __restrict__ hb1_w,  const void* __restrict__ hb1_b,
    const void* __restrict__ hwf_w1, const void* __restrict__ hwf_b1,
    const void* __restrict__ hwf_w2, const void* __restrict__ hwf_b2,
    const void* __restrict__ v_w1,   const void* __restrict__ v_b1,
    const void* __restrict__ v_w2,   const void* __restrict__ v_b2,
    float* __restrict__ w1_ws, float* __restrict__ b1_ws,
    float* __restrict__ wf_ws, float* __restrict__ v_ws,
    int* __restrict__ flag)
{
  __shared__ float s[128];
  __shared__ float h1[64];
  __shared__ float hf[64];
  __shared__ float vh[32];
  const int n = blockIdx.x;
  const int tid = threadIdx.x;

  // inline dtype detect on first 128 u16 words of states (~N(0,1), no zeros)
  const u16* sr = (const u16*)states;
  unsigned int e0 = (sr[tid] >> 7) & 0xFF;
  unsigned int e1 = (sr[tid + 64] >> 7) & 0xFF;
  unsigned long long bl0 = __ballot(e0 >= 97 && e0 <= 141);
  unsigned long long bl1 = __ballot(e1 >= 97 && e1 <= 141);
  int bf = (__popcll(bl0) + __popcll(bl1) >= 104) ? 1 : 0;
  if (tid == 0) *flag = bf;   // all blocks write same value (benign)

  if (bf)
    mlp_body<1>(states, hw1_w1, hw1_b1, hw1_w2, hw1_b2, hb1_w, hb1_b,
                hwf_w1, hwf_b1, hwf_w2, hwf_b2, v_w1, v_b1, v_w2, v_b2,
                w1_ws, b1_ws, wf_ws, v_ws, n, tid, s, h1, hf, vh);
  else
    mlp_body<0>(states, hw1_w1, hw1_b1, hw1_w2, hw1_b2, hb1_w, hb1_b,
                hwf_w1, hwf_b1, hwf_w2, hwf_b2, v_w1, v_b1, v_w2, v_b2,
                w1_ws, b1_ws, wf_ws, v_ws, n, tid, s, h1, hf, vh);
}

// ======= Kernel 2: 2 tasks per 128-thread block, one wave per task,
//         atomic-free scan projections + uniform-b128 conv taps (= R8) =======
__global__ __launch_bounds__(128) void k_perembed(
    const void* __restrict__ aq,          // (1024, 8, 51)
    const float* __restrict__ w1_ws, const float* __restrict__ b1_ws,
    const float* __restrict__ wf_ws, float* __restrict__ xw_ws,
    const int* __restrict__ flag)
{
  __shared__ __align__(16) float Ab[2][520];
  __shared__ __align__(16) float Bb[2][520];
  __shared__ __align__(16) float kvsb[2][56];
  __shared__ float gAb[2][53];
  __shared__ float gBb[2][54];

  const int w    = threadIdx.x >> 6;
  const int lane = threadIdx.x & 63;
  const int task = blockIdx.x * 2 + w;
  const int n = task >> 5;
  const int e = task & 31;
  const int bf = *flag;

  float* A   = Ab[w];
  float* B   = Bb[w];
  float* kvs = kvsb[w];
  float* gA  = gAb[w];
  float* gB  = gBb[w];

  // ---- prefetch: 8 agent probs, w1 row, scalars ----
  float pv[8];
  if (bf) {
    const u16* p = (const u16*)aq + n * 408 + lane;
#pragma unroll
    for (int a = 0; a < 8; ++a) pv[a] = (lane < 51) ? bf2f(p[a * 51]) : 0.f;
  } else {
    const float* p = (const float*)aq + n * 408 + lane;
#pragma unroll
    for (int a = 0; a < 8; ++a) pv[a] = (lane < 51) ? p[a * 51] : 0.f;
  }
  float wreg = (lane < 8) ? w1_ws[n * 256 + e * 8 + lane] : 0.f;
  float b1v  = b1_ws[n * 32 + e];
  float wfv  = wf_ws[n * 32 + e];

  // ---- seed: agent 0 projection (scan) -> A at base 64 ----
  float wv0 = __shfl(wreg, 0);
  int ML0, MH0;
  proj_bounds(wv0, ML0, MH0);
  {
    float pa = pv[0];
    proj_scan(gA, gB, 51, lane, [&](int t, bool act, float& sup, float& p) {
      sup = (-10.0f + 0.4f * (float)t) * wv0;
      p = act ? pa : 0.f;
    });
  }
  if (lane <= MH0 - ML0)
    A[64 + ML0 + lane] = gA[ML0 + lane] + gB[ML0 + lane];
  WAVE_SYNC();

  int LQ = 64 + ML0, HQ = 64 + MH0;
  float* q = A;
  float* qn = B;
#pragma unroll
  for (int a = 1; a < 8; ++a) {
    float wv = __shfl(wreg, a);
    int ML, MH;
    proj_bounds(wv, ML, MH);
    int T = MH - ML;
    int W = (T + 4) & ~3;                 // >= T+1, mult of 4
    float pa = pv[a];
    proj_scan(gA, gB, 51, lane, [&](int t, bool act, float& sup, float& p) {
      sup = (-10.0f + 0.4f * (float)t) * wv;
      p = act ? pa : 0.f;
    });
    if (lane < W)     kvs[lane] = (lane <= T) ? (gA[ML + lane] + gB[ML + lane]) : 0.f;
    if (lane < W - 1) q[LQ - 1 - lane] = 0.f;
    if (lane < T)     q[HQ + 1 + lane] = 0.f;
    WAVE_SYNC();
    conv_pad2(q, qn, kvs, ML, W, T, LQ, HQ, lane, 64);
    WAVE_SYNC();
    LQ += ML; HQ += MH;
    float* t_ = q; q = qn; qn = t_;
  }

  // ---- elu projection (chunked scan over claimed span) ----
  {
    int span = HQ - LQ + 1;
    int LQl = LQ;
    const float* qf = q;
    proj_scan(gA, gB, span, lane, [&](int t, bool act, float& sup, float& p) {
      int tg = (LQl - 64) + t;            // grid index in [0,400]
      float raw = (-80.0f + 0.4f * (float)tg) + b1v;
      sup = (raw > 0.f) ? raw : expm1f(raw);
      p = act ? qf[LQl + t] : 0.f;
    });
  }
  WAVE_SYNC();

  // ---- wf projection: x2 (in gA/gB) -> xw ----
  float x2v = (lane < 51) ? (gA[lane] + gB[lane]) : 0.f;
  WAVE_SYNC();                            // fence: read before re-zero
  int MLf, MHf;
  proj_bounds(wfv, MLf, MHf);
  proj_scan(gA, gB, 51, lane, [&](int t, bool act, float& sup, float& p) {
    sup = (-10.0f + 0.4f * (float)t) * wfv;
    p = act ? x2v : 0.f;
  });
  WAVE_SYNC();
  if (lane <= MHf - MLf)
    xw_ws[task * 51 + MLf + lane] = gA[MLf + lane] + gB[MLf + lane];
}

// ====== Kernel 3: TREE convolution — conv is associative; depth 5 not 31 =====
// 32 leaves (xw rows on claimed supports) -> 16 -> 8 -> 4 -> 2 -> 1.
// Layout per level: node k at meta_s, length meta_l, spacing align4(len)+G
// (G = max len at level + pad). Zero-gap invariant lets every conv run with
// uniform trip counts (no edge clamps): out[j] = sum_m B[m]*A[j-m], A reads
// beyond data land in zeroed gaps. Stale-buffer gaps re-zeroed at levels 2-4.
__global__ __launch_bounds__(256) void k_final(
    const float* __restrict__ xw_ws, const float* __restrict__ wf_ws,
    const float* __restrict__ v_ws,
    void* __restrict__ out, const int* __restrict__ flag)
{
  __shared__ __align__(16) float bufA[4608];
  __shared__ __align__(16) float bufB[4608];
  __shared__ int meta_s[63];   // node starts  (levels 0..5, base 64-(64>>c))
  __shared__ int meta_l[63];   // node lengths
  __shared__ int meta_ml[32];  // leaf grid ML
  __shared__ int meta_g[6];    // per-level gap G
  __shared__ int meta_mltot;   // sum of leaf MLs (grid offset of root)
  __shared__ float gA[53], gB[54];

  const int n    = blockIdx.x;
  const int tid  = threadIdx.x;
  const int lane = tid & 63;
  const int bf   = *flag;

  float wfreg = (lane < 32) ? wf_ws[n * 32 + lane] : 0.f;
  float vv    = v_ws[n];

  // zero both buffers (gap invariant for levels 0 and 1)
  for (int i = tid; i < 4608; i += 256) { bufA[i] = 0.f; bufB[i] = 0.f; }

  // ---- wave 0: build tree metadata with shuffle scans ----
  if (tid < 64) {
    int ml, mh;
    proj_bounds(wfreg, ml, mh);           // lanes>=32: wfreg=0 -> harmless
    if (lane < 32) meta_ml[lane] = ml;
    int msum = ml;
#pragma unroll
    for (int d = 1; d < 32; d <<= 1) msum += __shfl_xor(msum, d);
    if (lane == 0) meta_mltot = msum;     // sum over lanes 0..31

    int curlen = mh - ml + 1;
    int base = 0, Ncur = 32;
#pragma unroll
    for (int c = 0; c <= 5; ++c) {
      int lm = (lane < Ncur) ? curlen : 0;
#pragma unroll
      for (int d = 1; d < 32; d <<= 1) {
        int o = __shfl_xor(lm, d);
        lm = (o > lm) ? o : lm;
      }
      int G = (lm + 11) & ~3;             // >= maxW-1, mult of 4
      int sp = ((curlen + 3) & ~3) + G;   // 4-aligned spacing
      int inc = (lane < Ncur) ? sp : 0;
      int v0 = inc;
#pragma unroll
      for (int d = 1; d < 32; d <<= 1) {
        int u = __shfl_up(inc, d);
        if (lane >= d && lane < 32) inc += u;
      }
      if (lane < Ncur) {
        meta_s[base + lane] = 832 + (inc - v0);   // exclusive prefix
        meta_l[base + lane] = curlen;
      }
      if (lane == 0) meta_g[c] = G;
      if (c < 5) {
        int l0 = __shfl(curlen, 2 * lane);
        int l1 = __shfl(curlen, 2 * lane + 1);
        curlen = l0 + l1 - 1;
        base += Ncur;
        Ncur >>= 1;
      }
    }
  }
  __syncthreads();

  // ---- leaf fill: 8 threads per row, all global loads in one wave of issues
  {
    int g = tid >> 3, i = tid & 7;
    int s = meta_s[g], l = meta_l[g], ml = meta_ml[g];
    const float* row = xw_ws + (n * 32 + g) * 51 + ml;
    for (int i0 = i; i0 < l; i0 += 8) bufA[s + i0] = row[i0];
  }
  __syncthreads();

  // ---- 5 tree levels ----
#pragma unroll
  for (int c = 1; c <= 5; ++c) {
    const float* bin = (c & 1) ? bufA : bufB;
    float*       bout = (c & 1) ? bufB : bufA;
    const int Nout = 32 >> c;
    const int lg = 3 + c;                 // log2(groupsize)
    const int gs = 1 << lg;
    const int k  = tid >> lg;
    const int st = tid & (gs - 1);
    const int bc = 64 - (64 >> c);        // this level's meta base
    const int bp = 64 - (64 >> (c - 1));  // input level's meta base
    const int i0 = bp + 2 * k;
    const int sA = meta_s[i0];
    const int sB = meta_s[i0 + 1];
    const int lB = meta_l[i0 + 1];
    const int sO = meta_s[bc + k];
    const int lO = meta_l[bc + k];
    const int W  = (lB + 3) & ~3;

    for (int j = st * 2; j < lO; j += gs * 2) {
      const float* Ap = bin + sA + j + 1;
      float a0 = 0.f, a1 = 0.f;
      for (int m = 0; m < W; m += 4) {
        float4 k4 = *(const float4*)(bin + sB + m);
        float v0 = Ap[-m], v1 = Ap[-m - 1], v2 = Ap[-m - 2];
        float v3 = Ap[-m - 3], v4 = Ap[-m - 4];
        a0 = fmaf(k4.x, v1, fmaf(k4.y, v2, fmaf(k4.z, v3, fmaf(k4.w, v4, a0))));
        a1 = fmaf(k4.x, v0, fmaf(k4.y, v1, fmaf(k4.z, v2, fmaf(k4.w, v3, a1))));
      }
      bout[sO + j] = a0;
      if (j + 1 < lO) bout[sO + j + 1] = a1;
    }

    // re-zero gaps when writing into a stale buffer (levels 2..4); level 5's
    // extra regions are never read (scan touches only the root node's data)
    if (c >= 2 && c <= 4) {
      int G = meta_g[c];
      for (int p = tid; p < G; p += 256) bout[832 - G + p] = 0.f;
      for (int k2 = 0; k2 < Nout; ++k2) {
        int ss = meta_s[bc + k2] + meta_l[bc + k2];
        int ee = (k2 + 1 < Nout) ? meta_s[bc + k2 + 1]
                                 : ss + G + 3;
        for (int p = ss + tid; p < ee; p += 256) bout[p] = 0.f;
      }
    }
    __syncthreads();
  }

  // ---- final projection: root node (in bufB) + v, scan on wave 0 ----
  if (tid < 64) {
    int s5 = meta_s[62], l5 = meta_l[62], mlt = meta_mltot;
    const float* qf = bufB + s5;
    proj_scan(gA, gB, l5, lane, [&](int t, bool act, float& sup, float& p) {
      int tg = mlt + t;                   // grid index in [0,1600]
      sup = (-320.0f + 0.4f * (float)tg) + vv;
      p = act ? qf[t] : 0.f;
    });
    WAVE_SYNC();
    if (lane < 51) {
      float o = gA[lane] + gB[lane];
      if (bf) ((u16*)out)[n * 51 + lane] = f2bf(o);
      else    ((float*)out)[n * 51 + lane] = o;
    }
  }
}

// =========================== launcher ===========================
extern "C" void kernel_launch(void* const* d_in, const int* in_sizes, int n_in,
                              void* d_out, int out_size, void* d_ws, size_t ws_size,
                              hipStream_t stream)
{
  float* ws    = (float*)d_ws;
  float* w1_ws = ws;                       // 1024*256
  float* b1_ws = w1_ws + 1024 * 256;       // 1024*32
  float* wf_ws = b1_ws + 1024 * 32;        // 1024*32
  float* v_ws  = wf_ws + 1024 * 32;        // 1024
  float* xw_ws = v_ws  + 1024;             // 1024*32*51
  int*   flag  = (int*)(xw_ws + 1024 * 32 * 51);

  k_mlp<<<1024, 64, 0, stream>>>(d_in[1],
      d_in[2], d_in[3], d_in[4], d_in[5], d_in[6], d_in[7],
      d_in[8], d_in[9], d_in[10], d_in[11], d_in[12], d_in[13],
      d_in[14], d_in[15],
      w1_ws, b1_ws, wf_ws, v_ws, flag);

  k_perembed<<<16384, 128, 0, stream>>>(d_in[0], w1_ws, b1_ws, wf_ws, xw_ws, flag);

  k_final<<<1024, 256, 0, stream>>>(xw_ws, wf_ws, v_ws, d_out, flag);
}

// Round 10
// 248.696 us; speedup vs baseline: 2.0994x; 1.0053x over previous
//
#include <hip/hip_runtime.h>
#include <hip/hip_bf16.h>
#include <math.h>

typedef unsigned short u16;

// Compiler memory fence + drain of this wave's LDS ops. Each task's LDS region
// is touched by exactly ONE wave; same-wave DS ops execute in order.
#define WAVE_SYNC() asm volatile("s_waitcnt lgkmcnt(0)" ::: "memory")

// ---------- dtype helpers ----------
__device__ __forceinline__ float bf2f(u16 u) {
  union { unsigned int i; float f; } c;
  c.i = ((unsigned int)u) << 16;
  return c.f;
}
__device__ __forceinline__ float bflo(unsigned int u) {
  union { unsigned int i; float f; } c; c.i = u << 16; return c.f;
}
__device__ __forceinline__ float bfhi(unsigned int u) {
  union { unsigned int i; float f; } c; c.i = u & 0xffff0000u; return c.f;
}
__device__ __forceinline__ u16 f2bf(float f) {
  union { float f; unsigned int i; } c;
  c.f = f;
  unsigned int x = c.i;
  unsigned int r = (x + 0x7fffu + ((x >> 16) & 1u)) >> 16; // RNE
  return (u16)r;
}

// Destination-bin bounds for proj of supports (-10+0.4t)*wv, t=0..50, wv>=0.
// Endpoints use IDENTICAL float ops as the projection => conservative-exact.
__device__ __forceinline__ void proj_bounds(float wv, int& ML, int& MH) {
  float smin = (-10.0f + 0.4f * 0.0f)  * wv;
  float smax = (-10.0f + 0.4f * 50.0f) * wv;
  float bmin = (fminf(fmaxf(smin, -10.0f), 10.0f) + 10.0f) / 0.4f;
  float bmax = (fminf(fmaxf(smax, -10.0f), 10.0f) + 10.0f) / 0.4f;
  ML = (int)floorf(bmin);
  MH = (int)ceilf(bmax);
}

// ---------- atomic-free projection via segmented scan (fallback + elu/wf) ---
template<typename SUPP>
__device__ __forceinline__ void proj_scan(float* __restrict__ g1,
                                          float* __restrict__ g2,
                                          int span, int lane, SUPP supp)
{
  if (lane < 52) g1[lane] = 0.f;
  if (lane < 53) g2[lane] = 0.f;
  float cml = 0.f, cmu = 0.f;
  int ck = -1;
  for (int base = 0; base < span; base += 64) {
    int t = base + lane;
    bool act = (t < span);
    int tc = act ? t : (span - 1);
    float sup, p;
    supp(tc, act, sup, p);
    float c  = fminf(fmaxf(sup, -10.0f), 10.0f);
    float b  = (c + 10.0f) / 0.4f;
    float l  = floorf(b);
    float u  = ceilf(b);
    float eq = (u == l) ? 1.0f : 0.0f;
    float ml = p * (u - b + eq);
    float mu = p * (b - l);
    int   li = (int)l;
    bool last = (base + 64 >= span);
    if (lane == 0 && ck >= 0) {
      if (ck == li) { ml += cml; mu += cmu; }
      else          { g1[ck] = cml; g2[ck + 1] = cmu; }
    }
#pragma unroll
    for (int d = 1; d < 64; d <<= 1) {
      int   lo = __shfl_up(li, d);
      float a1 = __shfl_up(ml, d);
      float a2 = __shfl_up(mu, d);
      bool same = (lane >= d) && (lo == li);
      ml += same ? a1 : 0.f;
      mu += same ? a2 : 0.f;
    }
    int ln = __shfl_down(li, 1);
    bool runend = (lane == 63) ? last : (ln != li);
    if (runend) { g1[li] = ml; g2[li + 1] = mu; }
    if (!last) {
      cml = __shfl(ml, 63);
      cmu = __shfl(mu, 63);
      ck  = __shfl(li, 63);
    }
  }
}

// ---------- convolution: uniform-b128 kernel taps + batched q reads ----------
__device__ __forceinline__ void conv_pad2(const float* __restrict__ q,
                                          float* __restrict__ qn,
                                          const float* __restrict__ kvs,
                                          int ML, int W, int T,
                                          int LQ, int HQ, int tid, int nthr)
{
  const int Lout = LQ + ML, Hout = HQ + ML + T;
  for (int J = Lout + tid; J <= Hout; J += nthr) {
    const float* qp = q + (J - ML);
    float acc = 0.f;
    for (int c = 0; c < W; c += 4) {
      float4 k4 = *(const float4*)(kvs + c);   // uniform address -> broadcast
      acc = fmaf(k4.x, qp[-c],     acc);
      acc = fmaf(k4.y, qp[-c - 1], acc);
      acc = fmaf(k4.z, qp[-c - 2], acc);
      acc = fmaf(k4.w, qp[-c - 3], acc);
    }
    qn[J] = acc;
  }
}

// =================== Kernel 1: hypernet MLPs (+ inline dtype detect) ========
template<int BF>
__device__ __forceinline__ float ldt(const void* p, int i) {
  if (BF) return bf2f(((const u16*)p)[i]);
  return ((const float*)p)[i];
}

template<int BF>
__device__ __forceinline__ float dot128_t(const void* w, int row, const float* s) {
  float acc = 0.f;
  if (BF) {
    const uint4* p = (const uint4*)((const u16*)w + row * 128);
#pragma unroll
    for (int i = 0; i < 16; ++i) {
      uint4 v = p[i];
      int b = i * 8;
      acc = fmaf(bflo(v.x), s[b + 0], acc); acc = fmaf(bfhi(v.x), s[b + 1], acc);
      acc = fmaf(bflo(v.y), s[b + 2], acc); acc = fmaf(bfhi(v.y), s[b + 3], acc);
      acc = fmaf(bflo(v.z), s[b + 4], acc); acc = fmaf(bfhi(v.z), s[b + 5], acc);
      acc = fmaf(bflo(v.w), s[b + 6], acc); acc = fmaf(bfhi(v.w), s[b + 7], acc);
    }
  } else {
    const float4* p = (const float4*)((const float*)w + row * 128);
#pragma unroll
    for (int i = 0; i < 32; ++i) {
      float4 v = p[i];
      int b = i * 4;
      acc = fmaf(v.x, s[b + 0], acc); acc = fmaf(v.y, s[b + 1], acc);
      acc = fmaf(v.z, s[b + 2], acc); acc = fmaf(v.w, s[b + 3], acc);
    }
  }
  return acc;
}

template<int BF>
__device__ __forceinline__ float dot64_t(const void* w, int row, const float* h) {
  float acc = 0.f;
  if (BF) {
    const uint4* p = (const uint4*)((const u16*)w + row * 64);
#pragma unroll
    for (int i = 0; i < 8; ++i) {
      uint4 v = p[i];
      int b = i * 8;
      acc = fmaf(bflo(v.x), h[b + 0], acc); acc = fmaf(bfhi(v.x), h[b + 1], acc);
      acc = fmaf(bflo(v.y), h[b + 2], acc); acc = fmaf(bfhi(v.y), h[b + 3], acc);
      acc = fmaf(bflo(v.z), h[b + 4], acc); acc = fmaf(bfhi(v.z), h[b + 5], acc);
      acc = fmaf(bflo(v.w), h[b + 6], acc); acc = fmaf(bfhi(v.w), h[b + 7], acc);
    }
  } else {
    const float4* p = (const float4*)((const float*)w + row * 64);
#pragma unroll
    for (int i = 0; i < 16; ++i) {
      float4 v = p[i];
      int b = i * 4;
      acc = fmaf(v.x, h[b + 0], acc); acc = fmaf(v.y, h[b + 1], acc);
      acc = fmaf(v.z, h[b + 2], acc); acc = fmaf(v.w, h[b + 3], acc);
    }
  }
  return acc;
}

template<int BF>
__device__ __forceinline__ void mlp_body(
    const void* states,
    const void* hw1_w1, const void* hw1_b1, const void* hw1_w2, const void* hw1_b2,
    const void* hb1_w,  const void* hb1_b,
    const void* hwf_w1, const void* hwf_b1, const void* hwf_w2, const void* hwf_b2,
    const void* v_w1,   const void* v_b1,   const void* v_w2,   const void* v_b2,
    float* w1_ws, float* b1_ws, float* wf_ws, float* v_ws,
    int n, int tid, float* s, float* h1, float* hf, float* vh)
{
  s[tid]      = ldt<BF>(states, n * 128 + tid);
  s[tid + 64] = ldt<BF>(states, n * 128 + 64 + tid);
  __syncthreads();

  h1[tid] = fmaxf(dot128_t<BF>(hw1_w1, tid, s) + ldt<BF>(hw1_b1, tid), 0.f);
  hf[tid] = fmaxf(dot128_t<BF>(hwf_w1, tid, s) + ldt<BF>(hwf_b1, tid), 0.f);
  if (tid < 32) {
    vh[tid] = fmaxf(dot128_t<BF>(v_w1, tid, s) + ldt<BF>(v_b1, tid), 0.f);
    b1_ws[n * 32 + tid] = dot128_t<BF>(hb1_w, tid, s) + ldt<BF>(hb1_b, tid);
  }
  __syncthreads();

#pragma unroll
  for (int k = 0; k < 4; ++k) {
    int o = tid + 64 * k;
    w1_ws[n * 256 + o] = fabsf(dot64_t<BF>(hw1_w2, o, h1) + ldt<BF>(hw1_b2, o));
  }
  if (tid < 32)
    wf_ws[n * 32 + tid] = fabsf(dot64_t<BF>(hwf_w2, tid, hf) + ldt<BF>(hwf_b2, tid));
  if (tid == 0) {
    float acc = ldt<BF>(v_b2, 0);
    for (int e = 0; e < 32; ++e) acc = fmaf(ldt<BF>(v_w2, e), vh[e], acc);
    v_ws[n] = acc;
  }
}

__global__ __launch_bounds__(64) void k_mlp(
    const void* __restrict__ states,
    const void* __restrict__ hw1_w1, const void* __restrict__ hw1_b1,
    const void* __restrict__ hw1_w2, const void* __restrict__ hw1_b2,
    const void* __restrict__ hb1_w,  const void* __restrict__ hb1_b,
    const void* __restrict__ hwf_w1, const void* __restrict__ hwf_b1,
    const void* __restrict__ hwf_w2, const void* __restrict__ hwf_b2,
    const void* __restrict__ v_w1,   const void* __restrict__ v_b1,
    const void* __restrict__ v_w2,   const void* __restrict__ v_b2,
    float* __restrict__ w1_ws, float* __restrict__ b1_ws,
    float* __restrict__ wf_ws, float* __restrict__ v_ws,
    int* __restrict__ flag)
{
  __shared__ float s[128];
  __shared__ float h1[64];
  __shared__ float hf[64];
  __shared__ float vh[32];
  const int n = blockIdx.x;
  const int tid = threadIdx.x;

  // inline dtype detect on first 128 u16 words of states (~N(0,1), no zeros)
  const u16* sr = (const u16*)states;
  unsigned int e0 = (sr[tid] >> 7) & 0xFF;
  unsigned int e1 = (sr[tid + 64] >> 7) & 0xFF;
  unsigned long long bl0 = __ballot(e0 >= 97 && e0 <= 141);
  unsigned long long bl1 = __ballot(e1 >= 97 && e1 <= 141);
  int bf = (__popcll(bl0) + __popcll(bl1) >= 104) ? 1 : 0;
  if (tid == 0) *flag = bf;   // all blocks write same value (benign)

  if (bf)
    mlp_body<1>(states, hw1_w1, hw1_b1, hw1_w2, hw1_b2, hb1_w, hb1_b,
                hwf_w1, hwf_b1, hwf_w2, hwf_b2, v_w1, v_b1, v_w2, v_b2,
                w1_ws, b1_ws, wf_ws, v_ws, n, tid, s, h1, hf, vh);
  else
    mlp_body<0>(states, hw1_w1, hw1_b1, hw1_w2, hw1_b2, hb1_w, hb1_b,
                hwf_w1, hwf_b1, hwf_w2, hwf_b2, v_w1, v_b1, v_w2, v_b2,
                w1_ws, b1_ws, wf_ws, v_ws, n, tid, s, h1, hf, vh);
}

// ======= Kernel 2: 2 tasks per 128-thread block, one wave per task.
// Agent projections via FUSED GATHER (4 agents x 16 bins x 2 rounds):
// bin j receives p*max(0, 1-|b(t)-j|) — the continuous form of the C51
// scatter weights (floor/ceil/eq discontinuities cancel), so ULP deviations
// from the reference's exact rounding are bounded and safe. b(t) is linear
// in t (clip only feeds the END bins, which take full tails), so each bin's
// t-window is an analytic inverse +/-1 guard. Tasks with any agent span>15
// fall back to the proven scan path. =======
__global__ __launch_bounds__(128) void k_perembed(
    const void* __restrict__ aq,          // (1024, 8, 51)
    const float* __restrict__ w1_ws, const float* __restrict__ b1_ws,
    const float* __restrict__ wf_ws, float* __restrict__ xw_ws,
    const int* __restrict__ flag)
{
  __shared__ __align__(16) float Ab[2][520];
  __shared__ __align__(16) float Bb[2][520];
  __shared__ __align__(16) float kv_all[2][8][16]; // gather-path kernels
  __shared__ __align__(16) float kvo[2][56];       // fallback kernel buffer
  __shared__ float p_lds[2][8][52];                // agent probs (row conflict-free)
  __shared__ float gAb[2][53];
  __shared__ float gBb[2][54];

  const int w    = threadIdx.x >> 6;
  const int lane = threadIdx.x & 63;
  const int task = blockIdx.x * 2 + w;
  const int n = task >> 5;
  const int e = task & 31;
  const int bf = *flag;

  float* A   = Ab[w];
  float* B   = Bb[w];
  float* gA  = gAb[w];
  float* gB  = gBb[w];
  float (*pl)[52] = p_lds[w];

  // ---- stage agent probs into LDS (banks (20a+t)%32 distinct per a) ----
  if (bf) {
    const u16* p = (const u16*)aq + n * 408 + lane;
    if (lane < 51) {
#pragma unroll
      for (int a = 0; a < 8; ++a) pl[a][lane] = bf2f(p[a * 51]);
    }
  } else {
    const float* p = (const float*)aq + n * 408 + lane;
    if (lane < 51) {
#pragma unroll
      for (int a = 0; a < 8; ++a) pl[a][lane] = p[a * 51];
    }
  }
  float wreg = (lane < 8) ? w1_ws[n * 256 + e * 8 + lane] : 0.f;
  float b1v  = b1_ws[n * 32 + e];
  float wfv  = wf_ws[n * 32 + e];

  // lanes 0..7: per-agent bounds
  int mlA = 0, mhA = 0;
  if (lane < 8) proj_bounds(wreg, mlA, mhA);
  unsigned long long wide = __ballot((lane < 8) && (mhA - mlA > 15));
  WAVE_SYNC();                            // p_lds visible for gather/scan

  int LQ, HQ;
  float* q = A;
  float* qn = B;

  if (wide == 0ull) {
    // ================= gather path =================
#pragma unroll
    for (int r = 0; r < 2; ++r) {
      int a  = 4 * r + (lane >> 4);
      int jj = lane & 15;
      float wv = __shfl(wreg, a);
      int ML = __shfl(mlA, a);
      int MH = __shfl(mhA, a);
      int T = MH - ML;
      int j = ML + jj;
      float ej = 0.4f * (float)j - 10.0f;  // value of bin-j center edge
      // t-window: b in (j-1, j+1) <=> s in (ej-0.4, ej+0.4); edge bins take tails
      float invw = 2.5f / wv;              // inf ok (v_cvt saturates)
      int tL = (jj == 0) ? 0  : (int)floorf((ej - 0.4f) * invw + 25.f) - 1;
      int tH = (jj >= T) ? 50 : (int)ceilf ((ej + 0.4f) * invw + 25.f) + 1;
      tL = tL < 0 ? 0 : tL;
      tH = tH > 50 ? 50 : tH;
      if (jj > T) { tL = 0; tH = -1; }     // inactive lane
      float acc = 0.f;
      float tf = (float)tL;
      const float* pb = pl[a];
      for (int t = tL; t <= tH; ++t) {
        float p = pb[t];
        float sup = (-10.0f + 0.4f * tf) * wv;
        float c = fminf(fmaxf(sup, -10.0f), 10.0f);
        float d = (c - ej) * 2.5f;         // ~ b - j (continuous weight)
        float wgt = fmaxf(0.f, 1.f - fabsf(d));
        acc = fmaf(p, wgt, acc);
        tf += 1.0f;
      }
      kv_all[w][a][jj] = (jj <= T) ? acc : 0.f;
    }
    WAVE_SYNC();

    // seed: agent 0 row into A (base 64)
    int ML0 = __shfl(mlA, 0), MH0 = __shfl(mhA, 0);
    if (lane <= MH0 - ML0) A[64 + ML0 + lane] = kv_all[w][0][lane];
    WAVE_SYNC();
    LQ = 64 + ML0; HQ = 64 + MH0;

#pragma unroll
    for (int a = 1; a < 8; ++a) {
      int ML = __shfl(mlA, a), MH = __shfl(mhA, a);
      int T = MH - ML;
      int W = (T + 4) & ~3;                // <= 16 in this path
      if (lane < W - 1) q[LQ - 1 - lane] = 0.f;
      if (lane < T)     q[HQ + 1 + lane] = 0.f;
      WAVE_SYNC();
      conv_pad2(q, qn, &kv_all[w][a][0], ML, W, T, LQ, HQ, lane, 64);
      WAVE_SYNC();
      LQ += ML; HQ += MH;
      float* t_ = q; q = qn; qn = t_;
    }
  } else {
    // ================= fallback: proven scan path =================
    float* kvs = kvo[w];
    float wv0 = __shfl(wreg, 0);
    int ML0 = __shfl(mlA, 0), MH0 = __shfl(mhA, 0);
    proj_scan(gA, gB, 51, lane, [&](int t, bool act, float& sup, float& p) {
      sup = (-10.0f + 0.4f * (float)t) * wv0;
      float pv = pl[0][t];
      p = act ? pv : 0.f;
    });
    if (lane <= MH0 - ML0)
      A[64 + ML0 + lane] = gA[ML0 + lane] + gB[ML0 + lane];
    WAVE_SYNC();
    LQ = 64 + ML0; HQ = 64 + MH0;

    for (int a = 1; a < 8; ++a) {
      float wv = __shfl(wreg, a);
      int ML = __shfl(mlA, a), MH = __shfl(mhA, a);
      int T = MH - ML;
      int W = (T + 4) & ~3;                // <= 56
      proj_scan(gA, gB, 51, lane, [&](int t, bool act, float& sup, float& p) {
        sup = (-10.0f + 0.4f * (float)t) * wv;
        float pv = pl[a][t];
        p = act ? pv : 0.f;
      });
      if (lane < W)     kvs[lane] = (lane <= T) ? (gA[ML + lane] + gB[ML + lane]) : 0.f;
      if (lane < W - 1) q[LQ - 1 - lane] = 0.f;
      if (lane < T)     q[HQ + 1 + lane] = 0.f;
      WAVE_SYNC();
      conv_pad2(q, qn, kvs, ML, W, T, LQ, HQ, lane, 64);
      WAVE_SYNC();
      LQ += ML; HQ += MH;
      float* t_ = q; q = qn; qn = t_;
    }
  }

  // ---- elu projection (chunked scan over claimed span) ----
  {
    int span = HQ - LQ + 1;
    int LQl = LQ;
    const float* qf = q;
    proj_scan(gA, gB, span, lane, [&](int t, bool act, float& sup, float& p) {
      int tg = (LQl - 64) + t;            // grid index in [0,400]
      float raw = (-80.0f + 0.4f * (float)tg) + b1v;
      sup = (raw > 0.f) ? raw : expm1f(raw);
      p = act ? qf[LQl + t] : 0.f;
    });
  }
  WAVE_SYNC();

  // ---- wf projection: x2 (in gA/gB) -> xw ----
  float x2v = (lane < 51) ? (gA[lane] + gB[lane]) : 0.f;
  WAVE_SYNC();                            // fence: read before re-zero
  int MLf, MHf;
  proj_bounds(wfv, MLf, MHf);
  proj_scan(gA, gB, 51, lane, [&](int t, bool act, float& sup, float& p) {
    sup = (-10.0f + 0.4f * (float)t) * wfv;
    p = act ? x2v : 0.f;
  });
  WAVE_SYNC();
  if (lane <= MHf - MLf)
    xw_ws[task * 51 + MLf + lane] = gA[MLf + lane] + gB[MLf + lane];
}

// ====== Kernel 3: TREE convolution — depth 5, unchanged from R9 =====
__global__ __launch_bounds__(256) void k_final(
    const float* __restrict__ xw_ws, const float* __restrict__ wf_ws,
    const float* __restrict__ v_ws,
    void* __restrict__ out, const int* __restrict__ flag)
{
  __shared__ __align__(16) float bufA[4608];
  __shared__ __align__(16) float bufB[4608];
  __shared__ int meta_s[63];
  __shared__ int meta_l[63];
  __shared__ int meta_ml[32];
  __shared__ int meta_g[6];
  __shared__ int meta_mltot;
  __shared__ float gA[53], gB[54];

  const int n    = blockIdx.x;
  const int tid  = threadIdx.x;
  const int lane = tid & 63;
  const int bf   = *flag;

  float wfreg = (lane < 32) ? wf_ws[n * 32 + lane] : 0.f;
  float vv    = v_ws[n];

  for (int i = tid; i < 4608; i += 256) { bufA[i] = 0.f; bufB[i] = 0.f; }

  if (tid < 64) {
    int ml, mh;
    proj_bounds(wfreg, ml, mh);
    if (lane < 32) meta_ml[lane] = ml;
    int msum = ml;
#pragma unroll
    for (int d = 1; d < 32; d <<= 1) msum += __shfl_xor(msum, d);
    if (lane == 0) meta_mltot = msum;

    int curlen = mh - ml + 1;
    int base = 0, Ncur = 32;
#pragma unroll
    for (int c = 0; c <= 5; ++c) {
      int lm = (lane < Ncur) ? curlen : 0;
#pragma unroll
      for (int d = 1; d < 32; d <<= 1) {
        int o = __shfl_xor(lm, d);
        lm = (o > lm) ? o : lm;
      }
      int G = (lm + 11) & ~3;
      int sp = ((curlen + 3) & ~3) + G;
      int inc = (lane < Ncur) ? sp : 0;
      int v0 = inc;
#pragma unroll
      for (int d = 1; d < 32; d <<= 1) {
        int u = __shfl_up(inc, d);
        if (lane >= d && lane < 32) inc += u;
      }
      if (lane < Ncur) {
        meta_s[base + lane] = 832 + (inc - v0);
        meta_l[base + lane] = curlen;
      }
      if (lane == 0) meta_g[c] = G;
      if (c < 5) {
        int l0 = __shfl(curlen, 2 * lane);
        int l1 = __shfl(curlen, 2 * lane + 1);
        curlen = l0 + l1 - 1;
        base += Ncur;
        Ncur >>= 1;
      }
    }
  }
  __syncthreads();

  {
    int g = tid >> 3, i = tid & 7;
    int s = meta_s[g], l = meta_l[g], ml = meta_ml[g];
    const float* row = xw_ws + (n * 32 + g) * 51 + ml;
    for (int i0 = i; i0 < l; i0 += 8) bufA[s + i0] = row[i0];
  }
  __syncthreads();

#pragma unroll
  for (int c = 1; c <= 5; ++c) {
    const float* bin = (c & 1) ? bufA : bufB;
    float*       bout = (c & 1) ? bufB : bufA;
    const int Nout = 32 >> c;
    const int lg = 3 + c;
    const int gs = 1 << lg;
    const int k  = tid >> lg;
    const int st = tid & (gs - 1);
    const int bc = 64 - (64 >> c);
    const int bp = 64 - (64 >> (c - 1));
    const int i0 = bp + 2 * k;
    const int sA = meta_s[i0];
    const int sB = meta_s[i0 + 1];
    const int lB = meta_l[i0 + 1];
    const int sO = meta_s[bc + k];
    const int lO = meta_l[bc + k];
    const int W  = (lB + 3) & ~3;

    for (int j = st * 2; j < lO; j += gs * 2) {
      const float* Ap = bin + sA + j + 1;
      float a0 = 0.f, a1 = 0.f;
      for (int m = 0; m < W; m += 4) {
        float4 k4 = *(const float4*)(bin + sB + m);
        float v0 = Ap[-m], v1 = Ap[-m - 1], v2 = Ap[-m - 2];
        float v3 = Ap[-m - 3], v4 = Ap[-m - 4];
        a0 = fmaf(k4.x, v1, fmaf(k4.y, v2, fmaf(k4.z, v3, fmaf(k4.w, v4, a0))));
        a1 = fmaf(k4.x, v0, fmaf(k4.y, v1, fmaf(k4.z, v2, fmaf(k4.w, v3, a1))));
      }
      bout[sO + j] = a0;
      if (j + 1 < lO) bout[sO + j + 1] = a1;
    }

    if (c >= 2 && c <= 4) {
      int G = meta_g[c];
      for (int p = tid; p < G; p += 256) bout[832 - G + p] = 0.f;
      for (int k2 = 0; k2 < Nout; ++k2) {
        int ss = meta_s[bc + k2] + meta_l[bc + k2];
        int ee = (k2 + 1 < Nout) ? meta_s[bc + k2 + 1]
                                 : ss + G + 3;
        for (int p = ss + tid; p < ee; p += 256) bout[p] = 0.f;
      }
    }
    __syncthreads();
  }

  if (tid < 64) {
    int s5 = meta_s[62], l5 = meta_l[62], mlt = meta_mltot;
    const float* qf = bufB + s5;
    proj_scan(gA, gB, l5, lane, [&](int t, bool act, float& sup, float& p) {
      int tg = mlt + t;
      sup = (-320.0f + 0.4f * (float)tg) + vv;
      p = act ? qf[t] : 0.f;
    });
    WAVE_SYNC();
    if (lane < 51) {
      float o = gA[lane] + gB[lane];
      if (bf) ((u16*)out)[n * 51 + lane] = f2bf(o);
      else    ((float*)out)[n * 51 + lane] = o;
    }
  }
}

// =========================== launcher ===========================
extern "C" void kernel_launch(void* const* d_in, const int* in_sizes, int n_in,
                              void* d_out, int out_size, void* d_ws, size_t ws_size,
                              hipStream_t stream)
{
  float* ws    = (float*)d_ws;
  float* w1_ws = ws;                       // 1024*256
  float* b1_ws = w1_ws + 1024 * 256;       // 1024*32
  float* wf_ws = b1_ws + 1024 * 32;        // 1024*32
  float* v_ws  = wf_ws + 1024 * 32;        // 1024
  float* xw_ws = v_ws  + 1024;             // 1024*32*51
  int*   flag  = (int*)(xw_ws + 1024 * 32 * 51);

  k_mlp<<<1024, 64, 0, stream>>>(d_in[1],
      d_in[2], d_in[3], d_in[4], d_in[5], d_in[6], d_in[7],
      d_in[8], d_in[9], d_in[10], d_in[11], d_in[12], d_in[13],
      d_in[14], d_in[15],
      w1_ws, b1_ws, wf_ws, v_ws, flag);

  k_perembed<<<16384, 128, 0, stream>>>(d_in[0], w1_ws, b1_ws, wf_ws, xw_ws, flag);

  k_final<<<1024, 256, 0, stream>>>(xw_ws, wf_ws, v_ws, d_out, flag);
}